// Round 7
// baseline (429.514 us; speedup 1.0000x reference)
//
#include <hip/hip_runtime.h>
#include <math.h>

// ---------------- problem constants ----------------
namespace {
constexpr int B_   = 2;
constexpr int NCAM = 6;
constexpr int BN   = 12;
constexpr int CIN  = 256;
constexpr int COUT = 80;
constexpr int DBIN = 16;
constexpr int NOUT = 96;            // DBIN + COUT
constexpr int HF = 32, WF = 88;
constexpr int HW = HF * WF;         // 2816
constexpr int BEVH = 128, BEVW = 128;
constexpr int NUMC = B_ * BEVH * BEVW;   // 32768
constexpr int NPTS = BN * DBIN * HW;     // 540672

// ws layout (byte offsets)
constexpr size_t MATS_OFF   = 0;                            // 12*24 f32
constexpr size_t WT_OFF     = 2048;                         // 24576 f32 = 98304
constexpr size_t YT_OFF     = 102400;                       // 12*2816*96 f32 = 12976128
                                                            // (reused as bevCHW after gather)
constexpr size_t CELL_OFF   = YT_OFF + 12976128;            // NPTS i32 = 2162688
constexpr size_t COUNTS_OFF = CELL_OFF + 2162688;           // NUMC i32 = 131072
constexpr size_t STARTS_OFF = COUNTS_OFF + 131072;          // (NUMC+1) i32, padded
constexpr size_t CURS_OFF   = STARTS_OFF + 131584;          // NUMC i32
constexpr size_t PLIST_OFF  = CURS_OFF + 131072;            // NPTS i32 (fused (row<<4)|d)
constexpr size_t PCELL_OFF  = PLIST_OFF + 2162688;          // NPTS i32 (cell per sorted pos)
constexpr size_t BEVHWC_OFF = PCELL_OFF + 2162688;          // NUMC*80 f32 = 10485760
}

// ---------------- f32 LU inverse, LAPACK gesv-style ----------------
template<int NM>
__device__ void inv_lu_f32(float* A, float* Y) {
    int piv[NM];
    for (int j = 0; j < NM; j++) {
        int p = j; float mx = fabsf(A[j*NM+j]);
        for (int i = j+1; i < NM; i++) { float v = fabsf(A[i*NM+j]); if (v > mx) { mx = v; p = i; } }
        piv[j] = p;
        if (p != j) for (int k = 0; k < NM; k++) { float t = A[j*NM+k]; A[j*NM+k] = A[p*NM+k]; A[p*NM+k] = t; }
        float r = __fdiv_rn(1.0f, A[j*NM+j]);
        for (int i = j+1; i < NM; i++) A[i*NM+j] = __fmul_rn(A[i*NM+j], r);
        for (int i = j+1; i < NM; i++) {
            float lij = A[i*NM+j];
            for (int k = j+1; k < NM; k++)
                A[i*NM+k] = __fsub_rn(A[i*NM+k], __fmul_rn(lij, A[j*NM+k]));
        }
    }
    for (int c = 0; c < NM; c++) {
        float x[NM];
        for (int i = 0; i < NM; i++) x[i] = 0.f;
        x[c] = 1.f;
        for (int j = 0; j < NM; j++) { int p = piv[j]; if (p != j) { float t = x[j]; x[j] = x[p]; x[p] = t; } }
        for (int k = 0; k < NM; k++) {
            float xk = x[k];
            for (int i = k+1; i < NM; i++) x[i] = __fsub_rn(x[i], __fmul_rn(xk, A[i*NM+k]));
        }
        for (int k = NM-1; k >= 0; k--) {
            float xk = __fdiv_rn(x[k], A[k*NM+k]);
            x[k] = xk;
            for (int i = 0; i < k; i++) x[i] = __fsub_rn(x[i], __fmul_rn(xk, A[i*NM+k]));
        }
        for (int i = 0; i < NM; i++) Y[i*NM+c] = x[i];
    }
}

// ---------------- 1. per-camera transforms (f32, reference semantics) -------------
__global__ void lss_prep_kernel(const float* __restrict__ l2i,
                                const float* __restrict__ aug,
                                float* __restrict__ mats) {
    int n = threadIdx.x;
    if (n >= BN) return;
    float A[16], IA[16];
    for (int i = 0; i < 16; i++) A[i] = l2i[n*16 + i];
    inv_lu_f32<4>(A, IA);
    float R[9], IR[9];
    for (int i = 0; i < 3; i++)
        for (int j = 0; j < 3; j++) R[i*3+j] = aug[n*16 + i*4 + j];
    inv_lu_f32<3>(R, IR);
    float* o = mats + n*24;
    for (int i = 0; i < 9; i++) o[i] = IR[i];
    o[9]  = aug[n*16 + 3];
    o[10] = aug[n*16 + 7];
    o[11] = aug[n*16 + 11];
    for (int i = 0; i < 3; i++)
        for (int j = 0; j < 3; j++) o[12 + i*3 + j] = IA[i*4 + j];
    o[21] = IA[3]; o[22] = IA[7]; o[23] = IA[11];
}

// ---------------- 2. transpose depthnet weights -> wT[c][96] ----------------
__global__ void lss_wt_kernel(const float* __restrict__ w_dep, float* __restrict__ wT) {
    int idx = blockIdx.x * 256 + threadIdx.x;   // 96*256 = 24576
    int o = idx / CIN, c = idx % CIN;
    wT[c * NOUT + o] = w_dep[idx];
}

// ---------------- 3. geometry: cell per point (f32, np semantics) ----------------
__global__ void lss_geom_kernel(const float* __restrict__ mats,
                                int* __restrict__ cellid,
                                int* __restrict__ counts) {
    int gp = blockIdx.x * 256 + threadIdx.x;    // [0, BN*HW)
    int lane = threadIdx.x & 63;
    int bn = gp / HW, p = gp % HW;
    const float* m = mats + bn * 24;
    int ph = p / WF, pw = p % WF;
    float u = ((float)pw + 0.5f) * 8.0f;
    float v = ((float)ph + 0.5f) * 8.0f;
    float q0 = __fsub_rn(u, m[9]);
    float q1 = __fsub_rn(v, m[10]);
    float q2 = __fsub_rn(1.0f, m[11]);
    float r0 = __fadd_rn(__fadd_rn(__fmul_rn(m[0], q0), __fmul_rn(m[1], q1)), __fmul_rn(m[2], q2));
    float r1 = __fadd_rn(__fadd_rn(__fmul_rn(m[3], q0), __fmul_rn(m[4], q1)), __fmul_rn(m[5], q2));
    float r2 = __fadd_rn(__fadd_rn(__fmul_rn(m[6], q0), __fmul_rn(m[7], q1)), __fmul_rn(m[8], q2));
    int b = bn / NCAM;
    for (int d = 0; d < DBIN; d++) {
        float dv = __fmul_rn((float)d + 0.5f, 2.8125f);
        float p0 = __fmul_rn(r0, dv);
        float p1 = __fmul_rn(r1, dv);
        float p2 = __fmul_rn(r2, dv);
        float px = __fadd_rn(__fadd_rn(__fadd_rn(__fmul_rn(m[12], p0), __fmul_rn(m[13], p1)), __fmul_rn(m[14], p2)), m[21]);
        float py = __fadd_rn(__fadd_rn(__fadd_rn(__fmul_rn(m[15], p0), __fmul_rn(m[16], p1)), __fmul_rn(m[17], p2)), m[22]);
        float pz = __fadd_rn(__fadd_rn(__fadd_rn(__fmul_rn(m[18], p0), __fmul_rn(m[19], p1)), __fmul_rn(m[20], p2)), m[23]);
        float fx = floorf(__fdiv_rn(__fsub_rn(px, -51.2f), 0.8f));
        float fy = floorf(__fdiv_rn(__fsub_rn(py, -51.2f), 0.8f));
        int cell = -1;
        if (fx >= 0.0f && fx < 128.0f && fy >= 0.0f && fy < 128.0f && pz >= -5.0f && pz < 3.0f)
            cell = b * (BEVH * BEVW) + (int)fy * BEVW + (int)fx;
        cellid[(bn * DBIN + d) * HW + p] = cell;
        int cprev = __shfl_up(cell, 1);
        bool leader = (lane == 0) || (cell != cprev);
        unsigned long long L = __ballot(leader);
        unsigned long long above = (lane == 63) ? 0ull : (L >> (lane + 1));
        int runlen = above ? __ffsll(above) : (64 - lane);
        if (leader && cell >= 0) atomicAdd(&counts[cell], runlen);
    }
}

// ---------------- 4. scan counts -> starts, cursors, total (single block) ---------
__global__ void lss_scan_kernel(const int* __restrict__ counts,
                                int* __restrict__ starts,
                                int* __restrict__ cursors) {
    __shared__ int sums[1024];
    int tid = threadIdx.x;
    int base = tid * 32;                 // 32768 / 1024
    int local[32];
    int s = 0;
    #pragma unroll
    for (int i = 0; i < 32; i++) { local[i] = s; s += counts[base + i]; }
    sums[tid] = s;
    __syncthreads();
    for (int off = 1; off < 1024; off <<= 1) {
        int v = 0;
        if (tid >= off) v = sums[tid - off];
        __syncthreads();
        if (tid >= off) sums[tid] += v;
        __syncthreads();
    }
    int offset = (tid > 0) ? sums[tid - 1] : 0;
    #pragma unroll
    for (int i = 0; i < 32; i++) {
        int st = offset + local[i];
        starts[base + i]  = st;
        cursors[base + i] = st;
    }
    if (tid == 1023) starts[NUMC] = sums[1023];   // total valid
}

// ---------------- 5. fill CSR (run-aggregated atomics, fused index) ---------------
__global__ void lss_fill_kernel(const int* __restrict__ cellid,
                                int* __restrict__ cursors,
                                int* __restrict__ plist,
                                int* __restrict__ pcell) {
    int i = blockIdx.x * 256 + threadIdx.x;    // NPTS = 2112*256
    int lane = threadIdx.x & 63;
    int c = cellid[i];
    int bn  = i / (DBIN * HW);
    int rem = i % (DBIN * HW);
    int d   = rem / HW;
    int p   = rem % HW;
    int pf  = ((bn * HW + p) << 4) | d;
    int cprev = __shfl_up(c, 1);
    bool leader = (lane == 0) || (c != cprev);
    unsigned long long L = __ballot(leader);
    unsigned long long above = (lane == 63) ? 0ull : (L >> (lane + 1));
    int runlen = above ? __ffsll(above) : (64 - lane);
    unsigned long long below = L & (~0ull >> (63 - lane));
    int lead = 63 - __clzll(below);
    int rank = lane - lead;
    int bse = 0;
    if (leader && c >= 0) bse = atomicAdd(&cursors[c], runlen);
    bse = __shfl(bse, lead);
    if (c >= 0) {
        plist[bse + rank] = pf;
        pcell[bse + rank] = c;
    }
}

// ---------------- 6. depthnet GEMM + softmax ----------------
// r6 structure, two fixes: __launch_bounds__(256,1) frees the VGPR budget so the
// 8-deep load pipeline actually stays in registers; chunk=8 (16 VGPRs of loads).
// wave w -> o-group [24w,24w+24); lane -> 2 consecutive px (float2).
__global__ __launch_bounds__(256, 1) void lss_gemm_kernel(const float* __restrict__ x,
                                                          const float* __restrict__ wT,
                                                          const float* __restrict__ b_dep,
                                                          float* __restrict__ yT) {
    int lane = threadIdx.x & 63;
    int wv   = threadIdx.x >> 6;
    int ob   = wv * 24;
    int px0  = blockIdx.x * 128 + lane * 2;   // 264 blocks; HW=22*128 -> bn uniform
    int bn = px0 / HW, p = px0 % HW;
    const float* xp = x + (size_t)bn * CIN * HW + p;
    float acc[24][2];
    #pragma unroll
    for (int o = 0; o < 24; o++) { acc[o][0] = 0.f; acc[o][1] = 0.f; }

    for (int cc = 0; cc < CIN; cc += 8) {
        float2 xb[8];
        #pragma unroll
        for (int u = 0; u < 8; u++)
            xb[u] = *(const float2*)(xp + (size_t)(cc + u) * HW);
        #pragma unroll
        for (int u = 0; u < 8; u++) {
            const float* wc = wT + (cc + u) * NOUT + ob;   // uniform -> s_load
            #pragma unroll
            for (int o = 0; o < 24; o++) {
                acc[o][0] = fmaf(wc[o], xb[u].x, acc[o][0]);
                acc[o][1] = fmaf(wc[o], xb[u].y, acc[o][1]);
            }
        }
    }
    #pragma unroll
    for (int o = 0; o < 24; o++) {
        float bi = b_dep[ob + o];
        acc[o][0] += bi;
        acc[o][1] += bi;
    }
    if (wv == 0) {
        #pragma unroll
        for (int j = 0; j < 2; j++) {
            float* yp = yT + (size_t)(px0 + j) * NOUT;
            float m = acc[0][j];
            #pragma unroll
            for (int o = 1; o < 16; o++) m = fmaxf(m, acc[o][j]);
            float e[16], s = 0.f;
            #pragma unroll
            for (int o = 0; o < 16; o++) { e[o] = expf(acc[o][j] - m); s += e[o]; }
            float inv = 1.f / s;
            #pragma unroll
            for (int o = 0; o < 16; o++) yp[o] = e[o] * inv;
            #pragma unroll
            for (int o = 16; o < 24; o++) yp[o] = acc[o][j];
        }
    } else {
        #pragma unroll
        for (int j = 0; j < 2; j++) {
            float* yp = yT + (size_t)(px0 + j) * NOUT + ob;
            #pragma unroll
            for (int o = 0; o < 24; o++) yp[o] = acc[o][j];
        }
    }
}

// ---------------- 7. chunked segmented gather -> bevHWC (atomic flush) ------------
__global__ __launch_bounds__(256) void lss_gather_kernel(const float* __restrict__ yT,
                                                         const int* __restrict__ plist,
                                                         const int* __restrict__ pcell,
                                                         const int* __restrict__ nvptr,
                                                         float* __restrict__ bevHWC) {
    int wv   = threadIdx.x >> 6;
    int lane = threadIdx.x & 63;
    int pos0 = (blockIdx.x * 4 + wv) * 64;
    int nv = *nvptr;
    if (pos0 >= nv) return;
    int n = min(64, nv - pos0);
    const int* pl = plist + pos0;
    const int* pc = pcell + pos0;
    float a0 = 0.f, a1 = 0.f;
    int cur = pc[0];
    for (int j = 0; j < n; j++) {
        int c = pc[j];                     // wave-uniform
        if (c != cur) {
            atomicAdd(&bevHWC[(size_t)cur * COUT + lane], a0);
            if (lane < 16) atomicAdd(&bevHWC[(size_t)cur * COUT + 64 + lane], a1);
            a0 = a1 = 0.f;
            cur = c;
        }
        int pf = pl[j];
        const float* yp = yT + (size_t)(pf >> 4) * NOUT;
        float dep = yp[pf & 15];
        a0 = fmaf(dep, yp[16 + lane], a0);
        if (lane < 16) a1 = fmaf(dep, yp[80 + lane], a1);
    }
    atomicAdd(&bevHWC[(size_t)cur * COUT + lane], a0);
    if (lane < 16) atomicAdd(&bevHWC[(size_t)cur * COUT + 64 + lane], a1);
}

// ---------------- 8. transpose HWC->CHW + normalize by count ----------------------
__global__ __launch_bounds__(256) void lss_tr_kernel(const float* __restrict__ bevHWC,
                                                     const int* __restrict__ counts,
                                                     float* __restrict__ bevCHW) {
    __shared__ float t[COUT][65];
    __shared__ float ic[64];
    int tid = threadIdx.x;
    int cellbase = blockIdx.x * 64;
    if (tid < 64) {
        int cnt = counts[cellbase + tid];
        ic[tid] = 1.f / fmaxf((float)cnt, 1.f);
    }
    const float* src = bevHWC + (size_t)cellbase * COUT;
    #pragma unroll
    for (int k = 0; k < 20; k++) {
        int idx = tid + k * 256;           // 5120 = 20*256
        int yx = idx / COUT, ch = idx % COUT;
        t[ch][yx] = src[idx];
    }
    __syncthreads();
    int b  = cellbase >> 14;
    int yx0 = cellbase & 16383;
    #pragma unroll
    for (int k = 0; k < 20; k++) {
        int idx = tid + k * 256;
        int ch = idx / 64, yxl = idx % 64;
        bevCHW[((size_t)(b * COUT + ch)) * (BEVH * BEVW) + yx0 + yxl] = t[ch][yxl] * ic[yxl];
    }
}

// ---------------- 9. 3x3 SAME conv — register-window, 4 rows/thread ---------------
// thread: 1 col x 4 rows x 8 och (acc 32); 6x3 window; weights 72 s_dwords per ci
// against 288 FMA (1:4). __launch_bounds__(256,1) frees registers.
// grid (32, 10) = 320 blocks x 4 waves = 1280 waves.
__global__ __launch_bounds__(256, 1) void lss_conv_kernel(const float* __restrict__ bev,
                                                          const float* __restrict__ w,
                                                          const float* __restrict__ bias,
                                                          float* __restrict__ out) {
    int bx = blockIdx.x;               // 0..31 = b*16 + ytile(8 rows)
    int og = blockIdx.y * 8;           // 10 groups
    int b  = bx >> 4;
    int y0 = (bx & 15) * 8;
    int x  = threadIdx.x & 127;
    int rg = threadIdx.x >> 7;         // 0 or 1
    int yb = y0 + rg * 4;              // first of this thread's 4 rows

    int offs[6][3];
    float msk[6][3];
    #pragma unroll
    for (int r = 0; r < 6; r++) {
        int yy = yb + r - 1;
        float ym = (yy >= 0 && yy < 128) ? 1.f : 0.f;
        int yc = min(max(yy, 0), 127);
        #pragma unroll
        for (int c = 0; c < 3; c++) {
            int xx = x + c - 1;
            float xm = (xx >= 0 && xx < 128) ? 1.f : 0.f;
            int xc = min(max(xx, 0), 127);
            offs[r][c] = yc * BEVW + xc;
            msk[r][c]  = ym * xm;
        }
    }

    float acc[8][4];
    #pragma unroll
    for (int o = 0; o < 8; o++)
        #pragma unroll
        for (int j = 0; j < 4; j++) acc[o][j] = 0.f;

    const float* pb = bev + (size_t)b * COUT * (BEVH * BEVW);
    for (int ci = 0; ci < COUT; ci++) {
        const float* pc = pb + (size_t)ci * (BEVH * BEVW);
        float win[6][3];
        #pragma unroll
        for (int r = 0; r < 6; r++)
            #pragma unroll
            for (int c = 0; c < 3; c++)
                win[r][c] = pc[offs[r][c]] * msk[r][c];
        #pragma unroll
        for (int o = 0; o < 8; o++) {
            const float* wp = w + ((size_t)(og + o) * COUT + ci) * 9;   // uniform -> s_load
            #pragma unroll
            for (int j = 0; j < 4; j++) {
                float a = acc[o][j];
                a = fmaf(wp[0], win[j][0],     a);
                a = fmaf(wp[1], win[j][1],     a);
                a = fmaf(wp[2], win[j][2],     a);
                a = fmaf(wp[3], win[j + 1][0], a);
                a = fmaf(wp[4], win[j + 1][1], a);
                a = fmaf(wp[5], win[j + 1][2], a);
                a = fmaf(wp[6], win[j + 2][0], a);
                a = fmaf(wp[7], win[j + 2][1], a);
                a = fmaf(wp[8], win[j + 2][2], a);
                acc[o][j] = a;
            }
        }
    }
    #pragma unroll
    for (int o = 0; o < 8; o++) {
        float bi = bias[og + o];
        #pragma unroll
        for (int j = 0; j < 4; j++)
            out[((size_t)(b * COUT + og + o) * BEVH + (yb + j)) * BEVW + x] = acc[o][j] + bi;
    }
}

// ---------------- launch ----------------
extern "C" void kernel_launch(void* const* d_in, const int* in_sizes, int n_in,
                              void* d_out, int out_size, void* d_ws, size_t ws_size,
                              hipStream_t stream) {
    (void)in_sizes; (void)n_in; (void)out_size; (void)ws_size;
    const float* x     = (const float*)d_in[0];
    const float* l2i   = (const float*)d_in[1];
    const float* aug   = (const float*)d_in[2];
    const float* w_dep = (const float*)d_in[3];
    const float* b_dep = (const float*)d_in[4];
    const float* w_ref = (const float*)d_in[5];
    const float* b_ref = (const float*)d_in[6];
    float* out = (float*)d_out;

    char* ws = (char*)d_ws;
    float* mats    = (float*)(ws + MATS_OFF);
    float* wT      = (float*)(ws + WT_OFF);
    float* yT      = (float*)(ws + YT_OFF);     // reused as bevCHW after gather
    float* bevCHW  = (float*)(ws + YT_OFF);
    int*   cellid  = (int*)(ws + CELL_OFF);
    int*   counts  = (int*)(ws + COUNTS_OFF);
    int*   starts  = (int*)(ws + STARTS_OFF);
    int*   cursors = (int*)(ws + CURS_OFF);
    int*   plist   = (int*)(ws + PLIST_OFF);
    int*   pcell   = (int*)(ws + PCELL_OFF);
    float* bevHWC  = (float*)(ws + BEVHWC_OFF);

    hipMemsetAsync(counts, 0, NUMC * sizeof(int), stream);
    hipMemsetAsync(bevHWC, 0, (size_t)NUMC * COUT * sizeof(float), stream);
    lss_prep_kernel<<<1, 64, 0, stream>>>(l2i, aug, mats);
    lss_wt_kernel<<<96, 256, 0, stream>>>(w_dep, wT);
    lss_geom_kernel<<<BN * HW / 256, 256, 0, stream>>>(mats, cellid, counts);
    lss_scan_kernel<<<1, 1024, 0, stream>>>(counts, starts, cursors);
    lss_fill_kernel<<<NPTS / 256, 256, 0, stream>>>(cellid, cursors, plist, pcell);
    lss_gemm_kernel<<<264, 256, 0, stream>>>(x, wT, b_dep, yT);
    lss_gather_kernel<<<NPTS / 256, 256, 0, stream>>>(yT, plist, pcell, starts + NUMC, bevHWC);
    lss_tr_kernel<<<NUMC / 64, 256, 0, stream>>>(bevHWC, counts, bevCHW);
    lss_conv_kernel<<<dim3(32, 10), 256, 0, stream>>>(bevCHW, w_ref, b_ref, out);
}

// Round 8
// 303.381 us; speedup vs baseline: 1.4158x; 1.4158x over previous
//
#include <hip/hip_runtime.h>
#include <math.h>

// ---------------- problem constants ----------------
namespace {
constexpr int B_   = 2;
constexpr int NCAM = 6;
constexpr int BN   = 12;
constexpr int CIN  = 256;
constexpr int COUT = 80;
constexpr int DBIN = 16;
constexpr int NOUT = 96;            // DBIN + COUT
constexpr int HF = 32, WF = 88;
constexpr int HW = HF * WF;         // 2816
constexpr int BEVH = 128, BEVW = 128;
constexpr int NUMC = B_ * BEVH * BEVW;   // 32768
constexpr int NPTS = BN * DBIN * HW;     // 540672

// ws layout (byte offsets)
constexpr size_t MATS_OFF   = 0;                            // 12*24 f32
constexpr size_t WHI_OFF    = 2048;                         // 24576 ushort = 49152
constexpr size_t WLO_OFF    = WHI_OFF + 49152;              // 24576 ushort = 49152
constexpr size_t YT_OFF     = 102400;                       // 12*2816*96 f32 = 12976128
                                                            // (reused as bevCHW after gather)
constexpr size_t CELL_OFF   = YT_OFF + 12976128;            // NPTS i32 = 2162688
constexpr size_t COUNTS_OFF = CELL_OFF + 2162688;           // NUMC i32 = 131072
constexpr size_t STARTS_OFF = COUNTS_OFF + 131072;          // (NUMC+1) i32, padded
constexpr size_t CURS_OFF   = STARTS_OFF + 131584;          // NUMC i32
constexpr size_t PLIST_OFF  = CURS_OFF + 131072;            // NPTS i32 (fused (row<<4)|d)
constexpr size_t PCELL_OFF  = PLIST_OFF + 2162688;          // NPTS i32 (cell per sorted pos)
constexpr size_t BEVHWC_OFF = PCELL_OFF + 2162688;          // NUMC*80 f32 = 10485760
}

using bf16x8 = __attribute__((ext_vector_type(8))) short;
using f32x4  = __attribute__((ext_vector_type(4))) float;

__device__ inline unsigned short bf16rne(float f) {
    unsigned u = __float_as_uint(f);
    unsigned r = (u + 0x7FFFu + ((u >> 16) & 1u)) >> 16;
    return (unsigned short)r;
}

// ---------------- f32 LU inverse, LAPACK gesv-style ----------------
template<int NM>
__device__ void inv_lu_f32(float* A, float* Y) {
    int piv[NM];
    for (int j = 0; j < NM; j++) {
        int p = j; float mx = fabsf(A[j*NM+j]);
        for (int i = j+1; i < NM; i++) { float v = fabsf(A[i*NM+j]); if (v > mx) { mx = v; p = i; } }
        piv[j] = p;
        if (p != j) for (int k = 0; k < NM; k++) { float t = A[j*NM+k]; A[j*NM+k] = A[p*NM+k]; A[p*NM+k] = t; }
        float r = __fdiv_rn(1.0f, A[j*NM+j]);
        for (int i = j+1; i < NM; i++) A[i*NM+j] = __fmul_rn(A[i*NM+j], r);
        for (int i = j+1; i < NM; i++) {
            float lij = A[i*NM+j];
            for (int k = j+1; k < NM; k++)
                A[i*NM+k] = __fsub_rn(A[i*NM+k], __fmul_rn(lij, A[j*NM+k]));
        }
    }
    for (int c = 0; c < NM; c++) {
        float x[NM];
        for (int i = 0; i < NM; i++) x[i] = 0.f;
        x[c] = 1.f;
        for (int j = 0; j < NM; j++) { int p = piv[j]; if (p != j) { float t = x[j]; x[j] = x[p]; x[p] = t; } }
        for (int k = 0; k < NM; k++) {
            float xk = x[k];
            for (int i = k+1; i < NM; i++) x[i] = __fsub_rn(x[i], __fmul_rn(xk, A[i*NM+k]));
        }
        for (int k = NM-1; k >= 0; k--) {
            float xk = __fdiv_rn(x[k], A[k*NM+k]);
            x[k] = xk;
            for (int i = 0; i < k; i++) x[i] = __fsub_rn(x[i], __fmul_rn(xk, A[i*NM+k]));
        }
        for (int i = 0; i < NM; i++) Y[i*NM+c] = x[i];
    }
}

// ---------------- 1. per-camera transforms (f32, reference semantics) -------------
__global__ void lss_prep_kernel(const float* __restrict__ l2i,
                                const float* __restrict__ aug,
                                float* __restrict__ mats) {
    int n = threadIdx.x;
    if (n >= BN) return;
    float A[16], IA[16];
    for (int i = 0; i < 16; i++) A[i] = l2i[n*16 + i];
    inv_lu_f32<4>(A, IA);
    float R[9], IR[9];
    for (int i = 0; i < 3; i++)
        for (int j = 0; j < 3; j++) R[i*3+j] = aug[n*16 + i*4 + j];
    inv_lu_f32<3>(R, IR);
    float* o = mats + n*24;
    for (int i = 0; i < 9; i++) o[i] = IR[i];
    o[9]  = aug[n*16 + 3];
    o[10] = aug[n*16 + 7];
    o[11] = aug[n*16 + 11];
    for (int i = 0; i < 3; i++)
        for (int j = 0; j < 3; j++) o[12 + i*3 + j] = IA[i*4 + j];
    o[21] = IA[3]; o[22] = IA[7]; o[23] = IA[11];
}

// ---------------- 2. split w_dep into bf16 hi/lo planes, [o][c] layout ------------
__global__ void lss_wt_kernel(const float* __restrict__ w_dep,
                              unsigned short* __restrict__ wHi,
                              unsigned short* __restrict__ wLo) {
    int idx = blockIdx.x * 256 + threadIdx.x;   // 96*256 = 24576, w_dep is [o][c]
    float f = w_dep[idx];
    unsigned short h = bf16rne(f);
    float hf = __uint_as_float((unsigned)h << 16);
    wHi[idx] = h;
    wLo[idx] = bf16rne(f - hf);
}

// ---------------- 3. geometry: cell per point (f32, np semantics) ----------------
__global__ void lss_geom_kernel(const float* __restrict__ mats,
                                int* __restrict__ cellid,
                                int* __restrict__ counts) {
    int gp = blockIdx.x * 256 + threadIdx.x;    // [0, BN*HW)
    int lane = threadIdx.x & 63;
    int bn = gp / HW, p = gp % HW;
    const float* m = mats + bn * 24;
    int ph = p / WF, pw = p % WF;
    float u = ((float)pw + 0.5f) * 8.0f;
    float v = ((float)ph + 0.5f) * 8.0f;
    float q0 = __fsub_rn(u, m[9]);
    float q1 = __fsub_rn(v, m[10]);
    float q2 = __fsub_rn(1.0f, m[11]);
    float r0 = __fadd_rn(__fadd_rn(__fmul_rn(m[0], q0), __fmul_rn(m[1], q1)), __fmul_rn(m[2], q2));
    float r1 = __fadd_rn(__fadd_rn(__fmul_rn(m[3], q0), __fmul_rn(m[4], q1)), __fmul_rn(m[5], q2));
    float r2 = __fadd_rn(__fadd_rn(__fmul_rn(m[6], q0), __fmul_rn(m[7], q1)), __fmul_rn(m[8], q2));
    int b = bn / NCAM;
    for (int d = 0; d < DBIN; d++) {
        float dv = __fmul_rn((float)d + 0.5f, 2.8125f);
        float p0 = __fmul_rn(r0, dv);
        float p1 = __fmul_rn(r1, dv);
        float p2 = __fmul_rn(r2, dv);
        float px = __fadd_rn(__fadd_rn(__fadd_rn(__fmul_rn(m[12], p0), __fmul_rn(m[13], p1)), __fmul_rn(m[14], p2)), m[21]);
        float py = __fadd_rn(__fadd_rn(__fadd_rn(__fmul_rn(m[15], p0), __fmul_rn(m[16], p1)), __fmul_rn(m[17], p2)), m[22]);
        float pz = __fadd_rn(__fadd_rn(__fadd_rn(__fmul_rn(m[18], p0), __fmul_rn(m[19], p1)), __fmul_rn(m[20], p2)), m[23]);
        float fx = floorf(__fdiv_rn(__fsub_rn(px, -51.2f), 0.8f));
        float fy = floorf(__fdiv_rn(__fsub_rn(py, -51.2f), 0.8f));
        int cell = -1;
        if (fx >= 0.0f && fx < 128.0f && fy >= 0.0f && fy < 128.0f && pz >= -5.0f && pz < 3.0f)
            cell = b * (BEVH * BEVW) + (int)fy * BEVW + (int)fx;
        cellid[(bn * DBIN + d) * HW + p] = cell;
        int cprev = __shfl_up(cell, 1);
        bool leader = (lane == 0) || (cell != cprev);
        unsigned long long L = __ballot(leader);
        unsigned long long above = (lane == 63) ? 0ull : (L >> (lane + 1));
        int runlen = above ? __ffsll(above) : (64 - lane);
        if (leader && cell >= 0) atomicAdd(&counts[cell], runlen);
    }
}

// ---------------- 4. scan counts -> starts, cursors, total (single block) ---------
__global__ void lss_scan_kernel(const int* __restrict__ counts,
                                int* __restrict__ starts,
                                int* __restrict__ cursors) {
    __shared__ int sums[1024];
    int tid = threadIdx.x;
    int base = tid * 32;                 // 32768 / 1024
    int local[32];
    int s = 0;
    #pragma unroll
    for (int i = 0; i < 32; i++) { local[i] = s; s += counts[base + i]; }
    sums[tid] = s;
    __syncthreads();
    for (int off = 1; off < 1024; off <<= 1) {
        int v = 0;
        if (tid >= off) v = sums[tid - off];
        __syncthreads();
        if (tid >= off) sums[tid] += v;
        __syncthreads();
    }
    int offset = (tid > 0) ? sums[tid - 1] : 0;
    #pragma unroll
    for (int i = 0; i < 32; i++) {
        int st = offset + local[i];
        starts[base + i]  = st;
        cursors[base + i] = st;
    }
    if (tid == 1023) starts[NUMC] = sums[1023];   // total valid
}

// ---------------- 5. fill CSR (run-aggregated atomics, fused index) ---------------
__global__ void lss_fill_kernel(const int* __restrict__ cellid,
                                int* __restrict__ cursors,
                                int* __restrict__ plist,
                                int* __restrict__ pcell) {
    int i = blockIdx.x * 256 + threadIdx.x;    // NPTS = 2112*256
    int lane = threadIdx.x & 63;
    int c = cellid[i];
    int bn  = i / (DBIN * HW);
    int rem = i % (DBIN * HW);
    int d   = rem / HW;
    int p   = rem % HW;
    int pf  = ((bn * HW + p) << 4) | d;
    int cprev = __shfl_up(c, 1);
    bool leader = (lane == 0) || (c != cprev);
    unsigned long long L = __ballot(leader);
    unsigned long long above = (lane == 63) ? 0ull : (L >> (lane + 1));
    int runlen = above ? __ffsll(above) : (64 - lane);
    unsigned long long below = L & (~0ull >> (63 - lane));
    int lead = 63 - __clzll(below);
    int rank = lane - lead;
    int bse = 0;
    if (leader && c >= 0) bse = atomicAdd(&cursors[c], runlen);
    bse = __shfl(bse, lead);
    if (c >= 0) {
        plist[bse + rank] = pf;
        pcell[bse + rank] = c;
    }
}

// ---------------- 6. depthnet GEMM via split-bf16 MFMA + softmax ------------------
// block: 256 thr = 4 waves; block px-tile = 64 (wave wv -> px [16wv,16wv+16)).
// Each wave: 16 px x 96 o = 6 acc tiles (f32x4 each). K chunked x64 into LDS
// (hi/lo bf16 planes, row stride 72 ushort -> 2-way bank aliasing = free).
// y = x*w emulated as hi*hi + hi*lo + lo*hi (lo*lo term ~2^-18, negligible).
// Fragments (m89/m92-verified): A/B [free=lane&15][k=quad*8+j]; D row=quad*4+reg
// (px), col=lane&15 (o). Softmax over o<16 = cross-lane within each 16-lane quad.
__global__ __launch_bounds__(256) void lss_gemm_kernel(const float* __restrict__ x,
                                                       const unsigned short* __restrict__ wHi,
                                                       const unsigned short* __restrict__ wLo,
                                                       const float* __restrict__ b_dep,
                                                       float* __restrict__ yT) {
    __shared__ unsigned short xs[2][64][72];    // [hi/lo][px][k]
    __shared__ unsigned short wsb[2][96][72];   // [hi/lo][o][k]

    int tid  = threadIdx.x;
    int tl   = tid & 63;          // px lane for staging
    int tc   = tid >> 6;          // c-group for staging / wave id
    int pxg0 = blockIdx.x * 64;   // 528 blocks; HW=44*64 -> bn uniform per block
    int bn   = pxg0 / HW;
    const float* xcol = x + (size_t)bn * CIN * HW + (pxg0 % HW) + tl;

    f32x4 acc[6];
    #pragma unroll
    for (int t = 0; t < 6; t++) acc[t] = (f32x4){0.f, 0.f, 0.f, 0.f};

    int lane = tid & 63;
    int wv   = tc;
    int n16  = lane & 15;
    int q    = lane >> 4;

    for (int k0 = 0; k0 < CIN; k0 += 64) {
        if (k0) __syncthreads();
        // stage x chunk: convert f32 -> bf16 hi/lo
        #pragma unroll 4
        for (int i = 0; i < 16; i++) {
            int kk = 4 * i + tc;
            float v = xcol[(size_t)(k0 + kk) * HW];
            unsigned short h = bf16rne(v);
            float hf = __uint_as_float((unsigned)h << 16);
            xs[0][tl][kk] = h;
            xs[1][tl][kk] = bf16rne(v - hf);
        }
        // stage w chunk: copy pre-split planes, [o][c] rows
        #pragma unroll
        for (int i = 0; i < 12; i++) {
            int idx = tid + i * 256;          // 0..3071 (2 planes * 96 o * 16 ushort4)
            int plane = idx / 1536;
            int rem   = idx - plane * 1536;
            int o     = rem >> 4;
            int j     = rem & 15;
            const unsigned short* src = (plane ? wLo : wHi) + o * 256 + k0 + 4 * j;
            *(uint2*)&wsb[plane][o][4 * j] = *(const uint2*)src;
        }
        __syncthreads();
        // compute: 2 k-steps of 32
        #pragma unroll
        for (int ks = 0; ks < 64; ks += 32) {
            bf16x8 ah = *(const bf16x8*)&xs[0][16 * wv + n16][q * 8 + ks];
            bf16x8 al = *(const bf16x8*)&xs[1][16 * wv + n16][q * 8 + ks];
            #pragma unroll
            for (int t = 0; t < 6; t++) {
                bf16x8 bh = *(const bf16x8*)&wsb[0][16 * t + n16][q * 8 + ks];
                bf16x8 bl = *(const bf16x8*)&wsb[1][16 * t + n16][q * 8 + ks];
                acc[t] = __builtin_amdgcn_mfma_f32_16x16x32_bf16(ah, bh, acc[t], 0, 0, 0);
                acc[t] = __builtin_amdgcn_mfma_f32_16x16x32_bf16(ah, bl, acc[t], 0, 0, 0);
                acc[t] = __builtin_amdgcn_mfma_f32_16x16x32_bf16(al, bh, acc[t], 0, 0, 0);
            }
        }
    }

    // epilogue: bias, softmax over o in [0,16) across the quad's 16 lanes
    float bias[6];
    #pragma unroll
    for (int t = 0; t < 6; t++) bias[t] = b_dep[16 * t + n16];
    #pragma unroll
    for (int r = 0; r < 4; r++) {
        int pxg = pxg0 + 16 * wv + 4 * q + r;
        float* yp = yT + (size_t)pxg * NOUT;
        float v0 = acc[0][r] + bias[0];
        float mx = v0;
        #pragma unroll
        for (int m = 1; m < 16; m <<= 1) mx = fmaxf(mx, __shfl_xor(mx, m));
        float e = expf(v0 - mx);
        float s = e;
        #pragma unroll
        for (int m = 1; m < 16; m <<= 1) s += __shfl_xor(s, m);
        yp[n16] = e / s;
        #pragma unroll
        for (int t = 1; t < 6; t++) yp[16 * t + n16] = acc[t][r] + bias[t];
    }
}

// ---------------- 7. chunked segmented gather -> bevHWC (atomic flush) ------------
__global__ __launch_bounds__(256) void lss_gather_kernel(const float* __restrict__ yT,
                                                         const int* __restrict__ plist,
                                                         const int* __restrict__ pcell,
                                                         const int* __restrict__ nvptr,
                                                         float* __restrict__ bevHWC) {
    int wv   = threadIdx.x >> 6;
    int lane = threadIdx.x & 63;
    int pos0 = (blockIdx.x * 4 + wv) * 64;
    int nv = *nvptr;
    if (pos0 >= nv) return;
    int n = min(64, nv - pos0);
    const int* pl = plist + pos0;
    const int* pc = pcell + pos0;
    float a0 = 0.f, a1 = 0.f;
    int cur = pc[0];
    for (int j = 0; j < n; j++) {
        int c = pc[j];                     // wave-uniform
        if (c != cur) {
            atomicAdd(&bevHWC[(size_t)cur * COUT + lane], a0);
            if (lane < 16) atomicAdd(&bevHWC[(size_t)cur * COUT + 64 + lane], a1);
            a0 = a1 = 0.f;
            cur = c;
        }
        int pf = pl[j];
        const float* yp = yT + (size_t)(pf >> 4) * NOUT;
        float dep = yp[pf & 15];
        a0 = fmaf(dep, yp[16 + lane], a0);
        if (lane < 16) a1 = fmaf(dep, yp[80 + lane], a1);
    }
    atomicAdd(&bevHWC[(size_t)cur * COUT + lane], a0);
    if (lane < 16) atomicAdd(&bevHWC[(size_t)cur * COUT + 64 + lane], a1);
}

// ---------------- 8. transpose HWC->CHW + normalize by count ----------------------
__global__ __launch_bounds__(256) void lss_tr_kernel(const float* __restrict__ bevHWC,
                                                     const int* __restrict__ counts,
                                                     float* __restrict__ bevCHW) {
    __shared__ float t[COUT][65];
    __shared__ float ic[64];
    int tid = threadIdx.x;
    int cellbase = blockIdx.x * 64;
    if (tid < 64) {
        int cnt = counts[cellbase + tid];
        ic[tid] = 1.f / fmaxf((float)cnt, 1.f);
    }
    const float* src = bevHWC + (size_t)cellbase * COUT;
    #pragma unroll
    for (int k = 0; k < 20; k++) {
        int idx = tid + k * 256;           // 5120 = 20*256
        int yx = idx / COUT, ch = idx % COUT;
        t[ch][yx] = src[idx];
    }
    __syncthreads();
    int b  = cellbase >> 14;
    int yx0 = cellbase & 16383;
    #pragma unroll
    for (int k = 0; k < 20; k++) {
        int idx = tid + k * 256;
        int ch = idx / 64, yxl = idx % 64;
        bevCHW[((size_t)(b * COUT + ch)) * (BEVH * BEVW) + yx0 + yxl] = t[ch][yxl] * ic[yxl];
    }
}

// ---------------- 9. 3x3 SAME conv — barrier-free register-window (r6 version) ----
__global__ __launch_bounds__(256) void lss_conv_kernel(const float* __restrict__ bev,
                                                       const float* __restrict__ w,
                                                       const float* __restrict__ bias,
                                                       float* __restrict__ out) {
    int bx = blockIdx.x;               // 0..63 = b*32 + ytile
    int og = blockIdx.y * 8;           // 10 groups
    int b  = bx >> 5;
    int y0 = (bx & 31) * 4;
    int x  = threadIdx.x & 127;
    int rg = threadIdx.x >> 7;         // 0 or 1
    int yb = y0 + rg * 2;              // first out row of this thread

    int offs[4][3];
    float msk[4][3];
    #pragma unroll
    for (int r = 0; r < 4; r++) {
        int yy = yb + r - 1;
        float ym = (yy >= 0 && yy < 128) ? 1.f : 0.f;
        int yc = min(max(yy, 0), 127);
        #pragma unroll
        for (int c = 0; c < 3; c++) {
            int xx = x + c - 1;
            float xm = (xx >= 0 && xx < 128) ? 1.f : 0.f;
            int xc = min(max(xx, 0), 127);
            offs[r][c] = yc * BEVW + xc;
            msk[r][c]  = ym * xm;
        }
    }

    float acc[8][2];
    #pragma unroll
    for (int o = 0; o < 8; o++) { acc[o][0] = 0.f; acc[o][1] = 0.f; }

    const float* pb = bev + (size_t)b * COUT * (BEVH * BEVW);
    for (int ci = 0; ci < COUT; ci++) {
        const float* pc = pb + (size_t)ci * (BEVH * BEVW);
        float win[4][3];
        #pragma unroll
        for (int r = 0; r < 4; r++)
            #pragma unroll
            for (int c = 0; c < 3; c++)
                win[r][c] = pc[offs[r][c]] * msk[r][c];
        #pragma unroll
        for (int o = 0; o < 8; o++) {
            const float* wp = w + ((size_t)(og + o) * COUT + ci) * 9;   // uniform -> s_load
            #pragma unroll
            for (int j = 0; j < 2; j++) {
                float a = acc[o][j];
                a = fmaf(wp[0], win[j][0],     a);
                a = fmaf(wp[1], win[j][1],     a);
                a = fmaf(wp[2], win[j][2],     a);
                a = fmaf(wp[3], win[j + 1][0], a);
                a = fmaf(wp[4], win[j + 1][1], a);
                a = fmaf(wp[5], win[j + 1][2], a);
                a = fmaf(wp[6], win[j + 2][0], a);
                a = fmaf(wp[7], win[j + 2][1], a);
                a = fmaf(wp[8], win[j + 2][2], a);
                acc[o][j] = a;
            }
        }
    }
    #pragma unroll
    for (int o = 0; o < 8; o++) {
        float bi = bias[og + o];
        #pragma unroll
        for (int j = 0; j < 2; j++)
            out[((size_t)(b * COUT + og + o) * BEVH + (yb + j)) * BEVW + x] = acc[o][j] + bi;
    }
}

// ---------------- launch ----------------
extern "C" void kernel_launch(void* const* d_in, const int* in_sizes, int n_in,
                              void* d_out, int out_size, void* d_ws, size_t ws_size,
                              hipStream_t stream) {
    (void)in_sizes; (void)n_in; (void)out_size; (void)ws_size;
    const float* x     = (const float*)d_in[0];
    const float* l2i   = (const float*)d_in[1];
    const float* aug   = (const float*)d_in[2];
    const float* w_dep = (const float*)d_in[3];
    const float* b_dep = (const float*)d_in[4];
    const float* w_ref = (const float*)d_in[5];
    const float* b_ref = (const float*)d_in[6];
    float* out = (float*)d_out;

    char* ws = (char*)d_ws;
    float* mats    = (float*)(ws + MATS_OFF);
    unsigned short* wHi = (unsigned short*)(ws + WHI_OFF);
    unsigned short* wLo = (unsigned short*)(ws + WLO_OFF);
    float* yT      = (float*)(ws + YT_OFF);     // reused as bevCHW after gather
    float* bevCHW  = (float*)(ws + YT_OFF);
    int*   cellid  = (int*)(ws + CELL_OFF);
    int*   counts  = (int*)(ws + COUNTS_OFF);
    int*   starts  = (int*)(ws + STARTS_OFF);
    int*   cursors = (int*)(ws + CURS_OFF);
    int*   plist   = (int*)(ws + PLIST_OFF);
    int*   pcell   = (int*)(ws + PCELL_OFF);
    float* bevHWC  = (float*)(ws + BEVHWC_OFF);

    hipMemsetAsync(counts, 0, NUMC * sizeof(int), stream);
    hipMemsetAsync(bevHWC, 0, (size_t)NUMC * COUT * sizeof(float), stream);
    lss_prep_kernel<<<1, 64, 0, stream>>>(l2i, aug, mats);
    lss_wt_kernel<<<96, 256, 0, stream>>>(w_dep, wHi, wLo);
    lss_geom_kernel<<<BN * HW / 256, 256, 0, stream>>>(mats, cellid, counts);
    lss_scan_kernel<<<1, 1024, 0, stream>>>(counts, starts, cursors);
    lss_fill_kernel<<<NPTS / 256, 256, 0, stream>>>(cellid, cursors, plist, pcell);
    lss_gemm_kernel<<<528, 256, 0, stream>>>(x, wHi, wLo, b_dep, yT);
    lss_gather_kernel<<<NPTS / 256, 256, 0, stream>>>(yT, plist, pcell, starts + NUMC, bevHWC);
    lss_tr_kernel<<<NUMC / 64, 256, 0, stream>>>(bevHWC, counts, bevCHW);
    lss_conv_kernel<<<dim3(64, 10), 256, 0, stream>>>(bevCHW, w_ref, b_ref, out);
}

// Round 9
// 278.662 us; speedup vs baseline: 1.5413x; 1.0887x over previous
//
#include <hip/hip_runtime.h>
#include <math.h>

// ---------------- problem constants ----------------
namespace {
constexpr int B_   = 2;
constexpr int NCAM = 6;
constexpr int BN   = 12;
constexpr int CIN  = 256;
constexpr int COUT = 80;
constexpr int DBIN = 16;
constexpr int NOUT = 96;            // DBIN + COUT
constexpr int HF = 32, WF = 88;
constexpr int HW = HF * WF;         // 2816
constexpr int BEVH = 128, BEVW = 128;
constexpr int NUMC = B_ * BEVH * BEVW;   // 32768
constexpr int NPTS = BN * DBIN * HW;     // 540672

// ws layout (byte offsets)
constexpr size_t MATS_OFF   = 0;                            // 12*24 f32
constexpr size_t WHI_OFF    = 2048;                         // 24576 ushort = 49152
constexpr size_t WLO_OFF    = WHI_OFF + 49152;              // 24576 ushort = 49152
constexpr size_t YT_OFF     = 102400;                       // 12*2816*96 f32 = 12976128
                                                            // (reused as bevCHW after gather)
constexpr size_t CELL_OFF   = YT_OFF + 12976128;            // NPTS i32 = 2162688
constexpr size_t COUNTS_OFF = CELL_OFF + 2162688;           // NUMC i32 = 131072
constexpr size_t STARTS_OFF = COUNTS_OFF + 131072;          // (NUMC+1) i32, padded
constexpr size_t CURS_OFF   = STARTS_OFF + 131584;          // NUMC i32
constexpr size_t PLIST_OFF  = CURS_OFF + 131072;            // NPTS i32 (fused (row<<4)|d)
constexpr size_t PCELL_OFF  = PLIST_OFF + 2162688;          // NPTS i32 (cell per sorted pos)
constexpr size_t BEVHWC_OFF = PCELL_OFF + 2162688;          // NUMC*80 f32 = 10485760
constexpr size_t WRH_OFF    = BEVHWC_OFF + 10485760;        // 80*864 ushort = 138240
constexpr size_t WRL_OFF    = WRH_OFF + 138240;             // 80*864 ushort = 138240
}

using bf16x8 = __attribute__((ext_vector_type(8))) short;
using f32x4  = __attribute__((ext_vector_type(4))) float;

__device__ inline unsigned short bf16rne(float f) {
    unsigned u = __float_as_uint(f);
    unsigned r = (u + 0x7FFFu + ((u >> 16) & 1u)) >> 16;
    return (unsigned short)r;
}

// ---------------- f32 LU inverse, LAPACK gesv-style ----------------
template<int NM>
__device__ void inv_lu_f32(float* A, float* Y) {
    int piv[NM];
    for (int j = 0; j < NM; j++) {
        int p = j; float mx = fabsf(A[j*NM+j]);
        for (int i = j+1; i < NM; i++) { float v = fabsf(A[i*NM+j]); if (v > mx) { mx = v; p = i; } }
        piv[j] = p;
        if (p != j) for (int k = 0; k < NM; k++) { float t = A[j*NM+k]; A[j*NM+k] = A[p*NM+k]; A[p*NM+k] = t; }
        float r = __fdiv_rn(1.0f, A[j*NM+j]);
        for (int i = j+1; i < NM; i++) A[i*NM+j] = __fmul_rn(A[i*NM+j], r);
        for (int i = j+1; i < NM; i++) {
            float lij = A[i*NM+j];
            for (int k = j+1; k < NM; k++)
                A[i*NM+k] = __fsub_rn(A[i*NM+k], __fmul_rn(lij, A[j*NM+k]));
        }
    }
    for (int c = 0; c < NM; c++) {
        float x[NM];
        for (int i = 0; i < NM; i++) x[i] = 0.f;
        x[c] = 1.f;
        for (int j = 0; j < NM; j++) { int p = piv[j]; if (p != j) { float t = x[j]; x[j] = x[p]; x[p] = t; } }
        for (int k = 0; k < NM; k++) {
            float xk = x[k];
            for (int i = k+1; i < NM; i++) x[i] = __fsub_rn(x[i], __fmul_rn(xk, A[i*NM+k]));
        }
        for (int k = NM-1; k >= 0; k--) {
            float xk = __fdiv_rn(x[k], A[k*NM+k]);
            x[k] = xk;
            for (int i = 0; i < k; i++) x[i] = __fsub_rn(x[i], __fmul_rn(xk, A[i*NM+k]));
        }
        for (int i = 0; i < NM; i++) Y[i*NM+c] = x[i];
    }
}

// ---------------- 1. per-camera transforms (f32, reference semantics) -------------
__global__ void lss_prep_kernel(const float* __restrict__ l2i,
                                const float* __restrict__ aug,
                                float* __restrict__ mats) {
    int n = threadIdx.x;
    if (n >= BN) return;
    float A[16], IA[16];
    for (int i = 0; i < 16; i++) A[i] = l2i[n*16 + i];
    inv_lu_f32<4>(A, IA);
    float R[9], IR[9];
    for (int i = 0; i < 3; i++)
        for (int j = 0; j < 3; j++) R[i*3+j] = aug[n*16 + i*4 + j];
    inv_lu_f32<3>(R, IR);
    float* o = mats + n*24;
    for (int i = 0; i < 9; i++) o[i] = IR[i];
    o[9]  = aug[n*16 + 3];
    o[10] = aug[n*16 + 7];
    o[11] = aug[n*16 + 11];
    for (int i = 0; i < 3; i++)
        for (int j = 0; j < 3; j++) o[12 + i*3 + j] = IA[i*4 + j];
    o[21] = IA[3]; o[22] = IA[7]; o[23] = IA[11];
}

// ---------------- 2a. split w_dep into bf16 hi/lo planes, [o][c] layout -----------
__global__ void lss_wt_kernel(const float* __restrict__ w_dep,
                              unsigned short* __restrict__ wHi,
                              unsigned short* __restrict__ wLo) {
    int idx = blockIdx.x * 256 + threadIdx.x;   // 96*256 = 24576, w_dep is [o][c]
    float f = w_dep[idx];
    unsigned short h = bf16rne(f);
    float hf = __uint_as_float((unsigned)h << 16);
    wHi[idx] = h;
    wLo[idx] = bf16rne(f - hf);
}

// ---------------- 2b. split w_ref into bf16 hi/lo, layout [o][k], k=(s,ci96) ------
__global__ void lss_wref_kernel(const float* __restrict__ w_ref,
                                unsigned short* __restrict__ wrh,
                                unsigned short* __restrict__ wrl) {
    int idx = blockIdx.x * 256 + threadIdx.x;   // 80*864 = 69120 = 270*256
    int o  = idx / 864;
    int k  = idx - o * 864;
    int s  = k / 96;
    int ci = k - s * 96;
    float f = (ci < COUT) ? w_ref[(size_t)(o * COUT + ci) * 9 + s] : 0.f;
    unsigned short h = bf16rne(f);
    float hf = __uint_as_float((unsigned)h << 16);
    wrh[idx] = h;
    wrl[idx] = bf16rne(f - hf);
}

// ---------------- 3. geometry: cell per point (f32, np semantics) ----------------
__global__ void lss_geom_kernel(const float* __restrict__ mats,
                                int* __restrict__ cellid,
                                int* __restrict__ counts) {
    int gp = blockIdx.x * 256 + threadIdx.x;    // [0, BN*HW)
    int lane = threadIdx.x & 63;
    int bn = gp / HW, p = gp % HW;
    const float* m = mats + bn * 24;
    int ph = p / WF, pw = p % WF;
    float u = ((float)pw + 0.5f) * 8.0f;
    float v = ((float)ph + 0.5f) * 8.0f;
    float q0 = __fsub_rn(u, m[9]);
    float q1 = __fsub_rn(v, m[10]);
    float q2 = __fsub_rn(1.0f, m[11]);
    float r0 = __fadd_rn(__fadd_rn(__fmul_rn(m[0], q0), __fmul_rn(m[1], q1)), __fmul_rn(m[2], q2));
    float r1 = __fadd_rn(__fadd_rn(__fmul_rn(m[3], q0), __fmul_rn(m[4], q1)), __fmul_rn(m[5], q2));
    float r2 = __fadd_rn(__fadd_rn(__fmul_rn(m[6], q0), __fmul_rn(m[7], q1)), __fmul_rn(m[8], q2));
    int b = bn / NCAM;
    for (int d = 0; d < DBIN; d++) {
        float dv = __fmul_rn((float)d + 0.5f, 2.8125f);
        float p0 = __fmul_rn(r0, dv);
        float p1 = __fmul_rn(r1, dv);
        float p2 = __fmul_rn(r2, dv);
        float px = __fadd_rn(__fadd_rn(__fadd_rn(__fmul_rn(m[12], p0), __fmul_rn(m[13], p1)), __fmul_rn(m[14], p2)), m[21]);
        float py = __fadd_rn(__fadd_rn(__fadd_rn(__fmul_rn(m[15], p0), __fmul_rn(m[16], p1)), __fmul_rn(m[17], p2)), m[22]);
        float pz = __fadd_rn(__fadd_rn(__fadd_rn(__fmul_rn(m[18], p0), __fmul_rn(m[19], p1)), __fmul_rn(m[20], p2)), m[23]);
        float fx = floorf(__fdiv_rn(__fsub_rn(px, -51.2f), 0.8f));
        float fy = floorf(__fdiv_rn(__fsub_rn(py, -51.2f), 0.8f));
        int cell = -1;
        if (fx >= 0.0f && fx < 128.0f && fy >= 0.0f && fy < 128.0f && pz >= -5.0f && pz < 3.0f)
            cell = b * (BEVH * BEVW) + (int)fy * BEVW + (int)fx;
        cellid[(bn * DBIN + d) * HW + p] = cell;
        int cprev = __shfl_up(cell, 1);
        bool leader = (lane == 0) || (cell != cprev);
        unsigned long long L = __ballot(leader);
        unsigned long long above = (lane == 63) ? 0ull : (L >> (lane + 1));
        int runlen = above ? __ffsll(above) : (64 - lane);
        if (leader && cell >= 0) atomicAdd(&counts[cell], runlen);
    }
}

// ---------------- 4. scan counts -> starts, cursors, total (single block) ---------
__global__ void lss_scan_kernel(const int* __restrict__ counts,
                                int* __restrict__ starts,
                                int* __restrict__ cursors) {
    __shared__ int sums[1024];
    int tid = threadIdx.x;
    int base = tid * 32;                 // 32768 / 1024
    int local[32];
    int s = 0;
    #pragma unroll
    for (int i = 0; i < 32; i++) { local[i] = s; s += counts[base + i]; }
    sums[tid] = s;
    __syncthreads();
    for (int off = 1; off < 1024; off <<= 1) {
        int v = 0;
        if (tid >= off) v = sums[tid - off];
        __syncthreads();
        if (tid >= off) sums[tid] += v;
        __syncthreads();
    }
    int offset = (tid > 0) ? sums[tid - 1] : 0;
    #pragma unroll
    for (int i = 0; i < 32; i++) {
        int st = offset + local[i];
        starts[base + i]  = st;
        cursors[base + i] = st;
    }
    if (tid == 1023) starts[NUMC] = sums[1023];   // total valid
}

// ---------------- 5. fill CSR (run-aggregated atomics, fused index) ---------------
__global__ void lss_fill_kernel(const int* __restrict__ cellid,
                                int* __restrict__ cursors,
                                int* __restrict__ plist,
                                int* __restrict__ pcell) {
    int i = blockIdx.x * 256 + threadIdx.x;    // NPTS = 2112*256
    int lane = threadIdx.x & 63;
    int c = cellid[i];
    int bn  = i / (DBIN * HW);
    int rem = i % (DBIN * HW);
    int d   = rem / HW;
    int p   = rem % HW;
    int pf  = ((bn * HW + p) << 4) | d;
    int cprev = __shfl_up(c, 1);
    bool leader = (lane == 0) || (c != cprev);
    unsigned long long L = __ballot(leader);
    unsigned long long above = (lane == 63) ? 0ull : (L >> (lane + 1));
    int runlen = above ? __ffsll(above) : (64 - lane);
    unsigned long long below = L & (~0ull >> (63 - lane));
    int lead = 63 - __clzll(below);
    int rank = lane - lead;
    int bse = 0;
    if (leader && c >= 0) bse = atomicAdd(&cursors[c], runlen);
    bse = __shfl(bse, lead);
    if (c >= 0) {
        plist[bse + rank] = pf;
        pcell[bse + rank] = c;
    }
}

// ---------------- 6. depthnet GEMM via split-bf16 MFMA + softmax ------------------
__global__ __launch_bounds__(256) void lss_gemm_kernel(const float* __restrict__ x,
                                                       const unsigned short* __restrict__ wHi,
                                                       const unsigned short* __restrict__ wLo,
                                                       const float* __restrict__ b_dep,
                                                       float* __restrict__ yT) {
    __shared__ unsigned short xs[2][64][72];    // [hi/lo][px][k]
    __shared__ unsigned short wsb[2][96][72];   // [hi/lo][o][k]

    int tid  = threadIdx.x;
    int tl   = tid & 63;          // px lane for staging
    int tc   = tid >> 6;          // c-group for staging / wave id
    int pxg0 = blockIdx.x * 64;   // 528 blocks; HW=44*64 -> bn uniform per block
    int bn   = pxg0 / HW;
    const float* xcol = x + (size_t)bn * CIN * HW + (pxg0 % HW) + tl;

    f32x4 acc[6];
    #pragma unroll
    for (int t = 0; t < 6; t++) acc[t] = (f32x4){0.f, 0.f, 0.f, 0.f};

    int lane = tid & 63;
    int wv   = tc;
    int n16  = lane & 15;
    int q    = lane >> 4;

    for (int k0 = 0; k0 < CIN; k0 += 64) {
        if (k0) __syncthreads();
        #pragma unroll 4
        for (int i = 0; i < 16; i++) {
            int kk = 4 * i + tc;
            float v = xcol[(size_t)(k0 + kk) * HW];
            unsigned short h = bf16rne(v);
            float hf = __uint_as_float((unsigned)h << 16);
            xs[0][tl][kk] = h;
            xs[1][tl][kk] = bf16rne(v - hf);
        }
        #pragma unroll
        for (int i = 0; i < 12; i++) {
            int idx = tid + i * 256;          // 0..3071 (2 planes * 96 o * 16 ushort4)
            int plane = idx / 1536;
            int rem   = idx - plane * 1536;
            int o     = rem >> 4;
            int j     = rem & 15;
            const unsigned short* src = (plane ? wLo : wHi) + o * 256 + k0 + 4 * j;
            *(uint2*)&wsb[plane][o][4 * j] = *(const uint2*)src;
        }
        __syncthreads();
        #pragma unroll
        for (int ks = 0; ks < 64; ks += 32) {
            bf16x8 ah = *(const bf16x8*)&xs[0][16 * wv + n16][q * 8 + ks];
            bf16x8 al = *(const bf16x8*)&xs[1][16 * wv + n16][q * 8 + ks];
            #pragma unroll
            for (int t = 0; t < 6; t++) {
                bf16x8 bh = *(const bf16x8*)&wsb[0][16 * t + n16][q * 8 + ks];
                bf16x8 bl = *(const bf16x8*)&wsb[1][16 * t + n16][q * 8 + ks];
                acc[t] = __builtin_amdgcn_mfma_f32_16x16x32_bf16(ah, bh, acc[t], 0, 0, 0);
                acc[t] = __builtin_amdgcn_mfma_f32_16x16x32_bf16(ah, bl, acc[t], 0, 0, 0);
                acc[t] = __builtin_amdgcn_mfma_f32_16x16x32_bf16(al, bh, acc[t], 0, 0, 0);
            }
        }
    }

    float bias[6];
    #pragma unroll
    for (int t = 0; t < 6; t++) bias[t] = b_dep[16 * t + n16];
    #pragma unroll
    for (int r = 0; r < 4; r++) {
        int pxg = pxg0 + 16 * wv + 4 * q + r;
        float* yp = yT + (size_t)pxg * NOUT;
        float v0 = acc[0][r] + bias[0];
        float mx = v0;
        #pragma unroll
        for (int m = 1; m < 16; m <<= 1) mx = fmaxf(mx, __shfl_xor(mx, m));
        float e = expf(v0 - mx);
        float s = e;
        #pragma unroll
        for (int m = 1; m < 16; m <<= 1) s += __shfl_xor(s, m);
        yp[n16] = e / s;
        #pragma unroll
        for (int t = 1; t < 6; t++) yp[16 * t + n16] = acc[t][r] + bias[t];
    }
}

// ---------------- 7. chunked segmented gather -> bevHWC (atomic flush) ------------
__global__ __launch_bounds__(256) void lss_gather_kernel(const float* __restrict__ yT,
                                                         const int* __restrict__ plist,
                                                         const int* __restrict__ pcell,
                                                         const int* __restrict__ nvptr,
                                                         float* __restrict__ bevHWC) {
    int wv   = threadIdx.x >> 6;
    int lane = threadIdx.x & 63;
    int pos0 = (blockIdx.x * 4 + wv) * 64;
    int nv = *nvptr;
    if (pos0 >= nv) return;
    int n = min(64, nv - pos0);
    const int* pl = plist + pos0;
    const int* pc = pcell + pos0;
    float a0 = 0.f, a1 = 0.f;
    int cur = pc[0];
    for (int j = 0; j < n; j++) {
        int c = pc[j];                     // wave-uniform
        if (c != cur) {
            atomicAdd(&bevHWC[(size_t)cur * COUT + lane], a0);
            if (lane < 16) atomicAdd(&bevHWC[(size_t)cur * COUT + 64 + lane], a1);
            a0 = a1 = 0.f;
            cur = c;
        }
        int pf = pl[j];
        const float* yp = yT + (size_t)(pf >> 4) * NOUT;
        float dep = yp[pf & 15];
        a0 = fmaf(dep, yp[16 + lane], a0);
        if (lane < 16) a1 = fmaf(dep, yp[80 + lane], a1);
    }
    atomicAdd(&bevHWC[(size_t)cur * COUT + lane], a0);
    if (lane < 16) atomicAdd(&bevHWC[(size_t)cur * COUT + 64 + lane], a1);
}

// ---------------- 8. transpose HWC->CHW + normalize by count ----------------------
__global__ __launch_bounds__(256) void lss_tr_kernel(const float* __restrict__ bevHWC,
                                                     const int* __restrict__ counts,
                                                     float* __restrict__ bevCHW) {
    __shared__ float t[COUT][65];
    __shared__ float ic[64];
    int tid = threadIdx.x;
    int cellbase = blockIdx.x * 64;
    if (tid < 64) {
        int cnt = counts[cellbase + tid];
        ic[tid] = 1.f / fmaxf((float)cnt, 1.f);
    }
    const float* src = bevHWC + (size_t)cellbase * COUT;
    #pragma unroll
    for (int k = 0; k < 20; k++) {
        int idx = tid + k * 256;           // 5120 = 20*256
        int yx = idx / COUT, ch = idx % COUT;
        t[ch][yx] = src[idx];
    }
    __syncthreads();
    int b  = cellbase >> 14;
    int yx0 = cellbase & 16383;
    #pragma unroll
    for (int k = 0; k < 20; k++) {
        int idx = tid + k * 256;
        int ch = idx / 64, yxl = idx % 64;
        bevCHW[((size_t)(b * COUT + ch)) * (BEVH * BEVW) + yx0 + yxl] = t[ch][yxl] * ic[yxl];
    }
}

// ---------------- 9. 3x3 conv via split-bf16 MFMA implicit GEMM -------------------
// block: 256 thr = 4 waves; output 8x8 px patch x 80 o. K = (shift s, ci pad 96).
// Input halo (10x10, 96 ci) staged per ci-chunk of 32 as bf16 hi/lo in LDS
// ([2][10][10][104]: 104-ushort ci-stride -> 2-way bank aliasing = free, 16B
// aligned). Weights pre-split [o][864] in global, A-frags loaded directly (L1).
// A=weights (D row=o), B=input (D col=px). 3-product split: hh + hl + lh.
// w0/w1: o 0..47 x px-half; w2/w3: o 48..79 x px-half. 6 barriers/block.
__global__ __launch_bounds__(256) void lss_conv_kernel(const float* __restrict__ bev,
                                                       const unsigned short* __restrict__ wrh,
                                                       const unsigned short* __restrict__ wrl,
                                                       const float* __restrict__ bias,
                                                       float* __restrict__ out) {
    __shared__ unsigned short inT[2][10][10][104];
    int tid = threadIdx.x;
    int blk = blockIdx.x;                  // 512
    int b   = blk >> 8;
    int y0  = ((blk >> 4) & 15) * 8;
    int x0  = (blk & 15) * 8;
    int lane = tid & 63, w = tid >> 6;
    int q = lane >> 4, n16 = lane & 15;
    int ow = w >> 1;                        // 0: o 0..47 (3 tiles), 1: o 48..79 (2)
    int pj = (w & 1) * 2;                   // px-tile pair base (each tile = 2 rows x 8)
    int pr = n16 >> 3, pc = n16 & 7;
    int NO = ow ? 2 : 3;
    int obase = ow * 48;
    int kq = 8 * q;
    int rowb0 = 2 * pj + pr;

    int woff[3];
    #pragma unroll
    for (int i = 0; i < 3; i++) woff[i] = (obase + 16 * i + n16) * 864 + kq;

    f32x4 acc[3][2];
    #pragma unroll
    for (int i = 0; i < 3; i++)
        #pragma unroll
        for (int j = 0; j < 2; j++) acc[i][j] = (f32x4){0.f, 0.f, 0.f, 0.f};

    const float* pb = bev + (size_t)b * COUT * (BEVH * BEVW);

    for (int cc = 0; cc < 3; cc++) {
        int ci0 = cc * 32;
        if (cc) __syncthreads();
        #pragma unroll
        for (int t = 0; t < 13; t++) {
            int idx = tid + t * 256;       // 3200 = 32 ci x 10 x 10
            if (idx < 3200) {
                int ci  = idx / 100;
                int rem = idx - ci * 100;
                int r   = rem / 10;
                int c   = rem - r * 10;
                int gy = y0 + r - 1, gx = x0 + c - 1;
                int gci = ci0 + ci;
                float v = 0.f;
                if (gy >= 0 && gy < BEVH && gx >= 0 && gx < BEVW && gci < COUT)
                    v = pb[((size_t)gci * BEVH + gy) * BEVW + gx];
                unsigned short h = bf16rne(v);
                float hf = __uint_as_float((unsigned)h << 16);
                inT[0][r][c][ci] = h;
                inT[1][r][c][ci] = bf16rne(v - hf);
            }
        }
        __syncthreads();
        #pragma unroll
        for (int s = 0; s < 9; s++) {
            int dy = s / 3, dx = s - dy * 3;
            int kb = s * 96 + ci0;
            bf16x8 bh[2], bl[2];
            #pragma unroll
            for (int j = 0; j < 2; j++) {
                int rr = rowb0 + 2 * j + dy;
                int ccol = pc + dx;
                bh[j] = *(const bf16x8*)&inT[0][rr][ccol][kq];
                bl[j] = *(const bf16x8*)&inT[1][rr][ccol][kq];
            }
            #pragma unroll
            for (int i = 0; i < 3; i++) {
                if (i < NO) {
                    bf16x8 ah = *(const bf16x8*)&wrh[woff[i] + kb];
                    bf16x8 al = *(const bf16x8*)&wrl[woff[i] + kb];
                    #pragma unroll
                    for (int j = 0; j < 2; j++) {
                        acc[i][j] = __builtin_amdgcn_mfma_f32_16x16x32_bf16(ah, bh[j], acc[i][j], 0, 0, 0);
                        acc[i][j] = __builtin_amdgcn_mfma_f32_16x16x32_bf16(ah, bl[j], acc[i][j], 0, 0, 0);
                        acc[i][j] = __builtin_amdgcn_mfma_f32_16x16x32_bf16(al, bh[j], acc[i][j], 0, 0, 0);
                    }
                }
            }
        }
    }
    #pragma unroll
    for (int i = 0; i < 3; i++) {
        if (i < NO) {
            #pragma unroll
            for (int j = 0; j < 2; j++) {
                int gy = y0 + 2 * (pj + j) + pr;
                int gx = x0 + pc;
                #pragma unroll
                for (int r = 0; r < 4; r++) {
                    int o = obase + 16 * i + 4 * q + r;
                    out[((size_t)(b * COUT + o) * BEVH + gy) * BEVW + gx] = acc[i][j][r] + bias[o];
                }
            }
        }
    }
}

// ---------------- launch ----------------
extern "C" void kernel_launch(void* const* d_in, const int* in_sizes, int n_in,
                              void* d_out, int out_size, void* d_ws, size_t ws_size,
                              hipStream_t stream) {
    (void)in_sizes; (void)n_in; (void)out_size; (void)ws_size;
    const float* x     = (const float*)d_in[0];
    const float* l2i   = (const float*)d_in[1];
    const float* aug   = (const float*)d_in[2];
    const float* w_dep = (const float*)d_in[3];
    const float* b_dep = (const float*)d_in[4];
    const float* w_ref = (const float*)d_in[5];
    const float* b_ref = (const float*)d_in[6];
    float* out = (float*)d_out;

    char* ws = (char*)d_ws;
    float* mats    = (float*)(ws + MATS_OFF);
    unsigned short* wHi = (unsigned short*)(ws + WHI_OFF);
    unsigned short* wLo = (unsigned short*)(ws + WLO_OFF);
    unsigned short* wrh = (unsigned short*)(ws + WRH_OFF);
    unsigned short* wrl = (unsigned short*)(ws + WRL_OFF);
    float* yT      = (float*)(ws + YT_OFF);     // reused as bevCHW after gather
    float* bevCHW  = (float*)(ws + YT_OFF);
    int*   cellid  = (int*)(ws + CELL_OFF);
    int*   counts  = (int*)(ws + COUNTS_OFF);
    int*   starts  = (int*)(ws + STARTS_OFF);
    int*   cursors = (int*)(ws + CURS_OFF);
    int*   plist   = (int*)(ws + PLIST_OFF);
    int*   pcell   = (int*)(ws + PCELL_OFF);
    float* bevHWC  = (float*)(ws + BEVHWC_OFF);

    hipMemsetAsync(counts, 0, NUMC * sizeof(int), stream);
    hipMemsetAsync(bevHWC, 0, (size_t)NUMC * COUT * sizeof(float), stream);
    lss_prep_kernel<<<1, 64, 0, stream>>>(l2i, aug, mats);
    lss_wt_kernel<<<96, 256, 0, stream>>>(w_dep, wHi, wLo);
    lss_wref_kernel<<<270, 256, 0, stream>>>(w_ref, wrh, wrl);
    lss_geom_kernel<<<BN * HW / 256, 256, 0, stream>>>(mats, cellid, counts);
    lss_scan_kernel<<<1, 1024, 0, stream>>>(counts, starts, cursors);
    lss_fill_kernel<<<NPTS / 256, 256, 0, stream>>>(cellid, cursors, plist, pcell);
    lss_gemm_kernel<<<528, 256, 0, stream>>>(x, wHi, wLo, b_dep, yT);
    lss_gather_kernel<<<NPTS / 256, 256, 0, stream>>>(yT, plist, pcell, starts + NUMC, bevHWC);
    lss_tr_kernel<<<NUMC / 64, 256, 0, stream>>>(bevHWC, counts, bevCHW);
    lss_conv_kernel<<<512, 256, 0, stream>>>(bevCHW, wrh, wrl, b_ref, out);
}

// Round 10
// 233.929 us; speedup vs baseline: 1.8361x; 1.1912x over previous
//
#include <hip/hip_runtime.h>
#include <math.h>

// ---------------- problem constants ----------------
namespace {
constexpr int B_   = 2;
constexpr int NCAM = 6;
constexpr int BN   = 12;
constexpr int CIN  = 256;
constexpr int COUT = 80;
constexpr int DBIN = 16;
constexpr int NOUT = 96;            // DBIN + COUT
constexpr int HF = 32, WF = 88;
constexpr int HW = HF * WF;         // 2816
constexpr int BEVH = 128, BEVW = 128;
constexpr int NUMC = B_ * BEVH * BEVW;   // 32768
constexpr int NPTS = BN * DBIN * HW;     // 540672

// ws layout (byte offsets)
constexpr size_t MATS_OFF   = 0;                            // 12*24 f32
constexpr size_t WHI_OFF    = 2048;                         // 24576 ushort = 49152
constexpr size_t WLO_OFF    = WHI_OFF + 49152;              // 24576 ushort = 49152
constexpr size_t YT_OFF     = 102400;                       // 12*2816*96 f32 = 12976128
                                                            // (reused as bevCHW after gather)
constexpr size_t CELL_OFF   = YT_OFF + 12976128;            // NPTS i32 = 2162688
constexpr size_t COUNTS_OFF = CELL_OFF + 2162688;           // NUMC i32 = 131072
constexpr size_t STARTS_OFF = COUNTS_OFF + 131072;          // (NUMC+1) i32, padded
constexpr size_t CURS_OFF   = STARTS_OFF + 131584;          // NUMC i32
constexpr size_t PLIST_OFF  = CURS_OFF + 131072;            // NPTS i32 (fused (row<<4)|d)
constexpr size_t PCELL_OFF  = PLIST_OFF + 2162688;          // NPTS i32 (cell per sorted pos)
constexpr size_t BEVHWC_OFF = PCELL_OFF + 2162688;          // NUMC*80 f32 = 10485760
constexpr size_t WRH_OFF    = BEVHWC_OFF + 10485760;        // 80*864 ushort = 138240
constexpr size_t WRL_OFF    = WRH_OFF + 138240;             // 80*864 ushort = 138240
}

using bf16x8 = __attribute__((ext_vector_type(8))) short;
using f32x4  = __attribute__((ext_vector_type(4))) float;

__device__ inline unsigned short bf16rne(float f) {
    unsigned u = __float_as_uint(f);
    unsigned r = (u + 0x7FFFu + ((u >> 16) & 1u)) >> 16;
    return (unsigned short)r;
}

// ---------------- f32 LU inverse, LAPACK gesv-style ----------------
template<int NM>
__device__ void inv_lu_f32(float* A, float* Y) {
    int piv[NM];
    for (int j = 0; j < NM; j++) {
        int p = j; float mx = fabsf(A[j*NM+j]);
        for (int i = j+1; i < NM; i++) { float v = fabsf(A[i*NM+j]); if (v > mx) { mx = v; p = i; } }
        piv[j] = p;
        if (p != j) for (int k = 0; k < NM; k++) { float t = A[j*NM+k]; A[j*NM+k] = A[p*NM+k]; A[p*NM+k] = t; }
        float r = __fdiv_rn(1.0f, A[j*NM+j]);
        for (int i = j+1; i < NM; i++) A[i*NM+j] = __fmul_rn(A[i*NM+j], r);
        for (int i = j+1; i < NM; i++) {
            float lij = A[i*NM+j];
            for (int k = j+1; k < NM; k++)
                A[i*NM+k] = __fsub_rn(A[i*NM+k], __fmul_rn(lij, A[j*NM+k]));
        }
    }
    for (int c = 0; c < NM; c++) {
        float x[NM];
        for (int i = 0; i < NM; i++) x[i] = 0.f;
        x[c] = 1.f;
        for (int j = 0; j < NM; j++) { int p = piv[j]; if (p != j) { float t = x[j]; x[j] = x[p]; x[p] = t; } }
        for (int k = 0; k < NM; k++) {
            float xk = x[k];
            for (int i = k+1; i < NM; i++) x[i] = __fsub_rn(x[i], __fmul_rn(xk, A[i*NM+k]));
        }
        for (int k = NM-1; k >= 0; k--) {
            float xk = __fdiv_rn(x[k], A[k*NM+k]);
            x[k] = xk;
            for (int i = 0; i < k; i++) x[i] = __fsub_rn(x[i], __fmul_rn(xk, A[i*NM+k]));
        }
        for (int i = 0; i < NM; i++) Y[i*NM+c] = x[i];
    }
}

// ---------------- 1. per-camera transforms (f32, reference semantics) -------------
__global__ void lss_prep_kernel(const float* __restrict__ l2i,
                                const float* __restrict__ aug,
                                float* __restrict__ mats) {
    int n = threadIdx.x;
    if (n >= BN) return;
    float A[16], IA[16];
    for (int i = 0; i < 16; i++) A[i] = l2i[n*16 + i];
    inv_lu_f32<4>(A, IA);
    float R[9], IR[9];
    for (int i = 0; i < 3; i++)
        for (int j = 0; j < 3; j++) R[i*3+j] = aug[n*16 + i*4 + j];
    inv_lu_f32<3>(R, IR);
    float* o = mats + n*24;
    for (int i = 0; i < 9; i++) o[i] = IR[i];
    o[9]  = aug[n*16 + 3];
    o[10] = aug[n*16 + 7];
    o[11] = aug[n*16 + 11];
    for (int i = 0; i < 3; i++)
        for (int j = 0; j < 3; j++) o[12 + i*3 + j] = IA[i*4 + j];
    o[21] = IA[3]; o[22] = IA[7]; o[23] = IA[11];
}

// ---------------- 2a. split w_dep into bf16 hi/lo planes, [o][c] layout -----------
__global__ void lss_wt_kernel(const float* __restrict__ w_dep,
                              unsigned short* __restrict__ wHi,
                              unsigned short* __restrict__ wLo) {
    int idx = blockIdx.x * 256 + threadIdx.x;   // 96*256 = 24576, w_dep is [o][c]
    float f = w_dep[idx];
    unsigned short h = bf16rne(f);
    float hf = __uint_as_float((unsigned)h << 16);
    wHi[idx] = h;
    wLo[idx] = bf16rne(f - hf);
}

// ---------------- 2b. split w_ref into bf16 hi/lo, layout [o][k], k=(s,ci96) ------
__global__ void lss_wref_kernel(const float* __restrict__ w_ref,
                                unsigned short* __restrict__ wrh,
                                unsigned short* __restrict__ wrl) {
    int idx = blockIdx.x * 256 + threadIdx.x;   // 80*864 = 69120 = 270*256
    int o  = idx / 864;
    int k  = idx - o * 864;
    int s  = k / 96;
    int ci = k - s * 96;
    float f = (ci < COUT) ? w_ref[(size_t)(o * COUT + ci) * 9 + s] : 0.f;
    unsigned short h = bf16rne(f);
    float hf = __uint_as_float((unsigned)h << 16);
    wrh[idx] = h;
    wrl[idx] = bf16rne(f - hf);
}

// ---------------- 3. geometry: cell per point (f32, np semantics) ----------------
__global__ void lss_geom_kernel(const float* __restrict__ mats,
                                int* __restrict__ cellid,
                                int* __restrict__ counts) {
    int gp = blockIdx.x * 256 + threadIdx.x;    // [0, BN*HW)
    int lane = threadIdx.x & 63;
    int bn = gp / HW, p = gp % HW;
    const float* m = mats + bn * 24;
    int ph = p / WF, pw = p % WF;
    float u = ((float)pw + 0.5f) * 8.0f;
    float v = ((float)ph + 0.5f) * 8.0f;
    float q0 = __fsub_rn(u, m[9]);
    float q1 = __fsub_rn(v, m[10]);
    float q2 = __fsub_rn(1.0f, m[11]);
    float r0 = __fadd_rn(__fadd_rn(__fmul_rn(m[0], q0), __fmul_rn(m[1], q1)), __fmul_rn(m[2], q2));
    float r1 = __fadd_rn(__fadd_rn(__fmul_rn(m[3], q0), __fmul_rn(m[4], q1)), __fmul_rn(m[5], q2));
    float r2 = __fadd_rn(__fadd_rn(__fmul_rn(m[6], q0), __fmul_rn(m[7], q1)), __fmul_rn(m[8], q2));
    int b = bn / NCAM;
    for (int d = 0; d < DBIN; d++) {
        float dv = __fmul_rn((float)d + 0.5f, 2.8125f);
        float p0 = __fmul_rn(r0, dv);
        float p1 = __fmul_rn(r1, dv);
        float p2 = __fmul_rn(r2, dv);
        float px = __fadd_rn(__fadd_rn(__fadd_rn(__fmul_rn(m[12], p0), __fmul_rn(m[13], p1)), __fmul_rn(m[14], p2)), m[21]);
        float py = __fadd_rn(__fadd_rn(__fadd_rn(__fmul_rn(m[15], p0), __fmul_rn(m[16], p1)), __fmul_rn(m[17], p2)), m[22]);
        float pz = __fadd_rn(__fadd_rn(__fadd_rn(__fmul_rn(m[18], p0), __fmul_rn(m[19], p1)), __fmul_rn(m[20], p2)), m[23]);
        float fx = floorf(__fdiv_rn(__fsub_rn(px, -51.2f), 0.8f));
        float fy = floorf(__fdiv_rn(__fsub_rn(py, -51.2f), 0.8f));
        int cell = -1;
        if (fx >= 0.0f && fx < 128.0f && fy >= 0.0f && fy < 128.0f && pz >= -5.0f && pz < 3.0f)
            cell = b * (BEVH * BEVW) + (int)fy * BEVW + (int)fx;
        cellid[(bn * DBIN + d) * HW + p] = cell;
        int cprev = __shfl_up(cell, 1);
        bool leader = (lane == 0) || (cell != cprev);
        unsigned long long L = __ballot(leader);
        unsigned long long above = (lane == 63) ? 0ull : (L >> (lane + 1));
        int runlen = above ? __ffsll(above) : (64 - lane);
        if (leader && cell >= 0) atomicAdd(&counts[cell], runlen);
    }
}

// ---------------- 4. scan counts -> starts, cursors, total (single block) ---------
__global__ void lss_scan_kernel(const int* __restrict__ counts,
                                int* __restrict__ starts,
                                int* __restrict__ cursors) {
    __shared__ int sums[1024];
    int tid = threadIdx.x;
    int base = tid * 32;                 // 32768 / 1024
    int local[32];
    int s = 0;
    #pragma unroll
    for (int i = 0; i < 32; i++) { local[i] = s; s += counts[base + i]; }
    sums[tid] = s;
    __syncthreads();
    for (int off = 1; off < 1024; off <<= 1) {
        int v = 0;
        if (tid >= off) v = sums[tid - off];
        __syncthreads();
        if (tid >= off) sums[tid] += v;
        __syncthreads();
    }
    int offset = (tid > 0) ? sums[tid - 1] : 0;
    #pragma unroll
    for (int i = 0; i < 32; i++) {
        int st = offset + local[i];
        starts[base + i]  = st;
        cursors[base + i] = st;
    }
    if (tid == 1023) starts[NUMC] = sums[1023];   // total valid
}

// ---------------- 5. fill CSR (run-aggregated atomics, fused index) ---------------
__global__ void lss_fill_kernel(const int* __restrict__ cellid,
                                int* __restrict__ cursors,
                                int* __restrict__ plist,
                                int* __restrict__ pcell) {
    int i = blockIdx.x * 256 + threadIdx.x;    // NPTS = 2112*256
    int lane = threadIdx.x & 63;
    int c = cellid[i];
    int bn  = i / (DBIN * HW);
    int rem = i % (DBIN * HW);
    int d   = rem / HW;
    int p   = rem % HW;
    int pf  = ((bn * HW + p) << 4) | d;
    int cprev = __shfl_up(c, 1);
    bool leader = (lane == 0) || (c != cprev);
    unsigned long long L = __ballot(leader);
    unsigned long long above = (lane == 63) ? 0ull : (L >> (lane + 1));
    int runlen = above ? __ffsll(above) : (64 - lane);
    unsigned long long below = L & (~0ull >> (63 - lane));
    int lead = 63 - __clzll(below);
    int rank = lane - lead;
    int bse = 0;
    if (leader && c >= 0) bse = atomicAdd(&cursors[c], runlen);
    bse = __shfl(bse, lead);
    if (c >= 0) {
        plist[bse + rank] = pf;
        pcell[bse + rank] = c;
    }
}

// ---------------- 6. depthnet GEMM via split-bf16 MFMA + softmax ------------------
__global__ __launch_bounds__(256) void lss_gemm_kernel(const float* __restrict__ x,
                                                       const unsigned short* __restrict__ wHi,
                                                       const unsigned short* __restrict__ wLo,
                                                       const float* __restrict__ b_dep,
                                                       float* __restrict__ yT) {
    __shared__ unsigned short xs[2][64][72];    // [hi/lo][px][k]
    __shared__ unsigned short wsb[2][96][72];   // [hi/lo][o][k]

    int tid  = threadIdx.x;
    int tl   = tid & 63;          // px lane for staging
    int tc   = tid >> 6;          // c-group for staging / wave id
    int pxg0 = blockIdx.x * 64;   // 528 blocks; HW=44*64 -> bn uniform per block
    int bn   = pxg0 / HW;
    const float* xcol = x + (size_t)bn * CIN * HW + (pxg0 % HW) + tl;

    f32x4 acc[6];
    #pragma unroll
    for (int t = 0; t < 6; t++) acc[t] = (f32x4){0.f, 0.f, 0.f, 0.f};

    int lane = tid & 63;
    int wv   = tc;
    int n16  = lane & 15;
    int q    = lane >> 4;

    for (int k0 = 0; k0 < CIN; k0 += 64) {
        if (k0) __syncthreads();
        #pragma unroll 4
        for (int i = 0; i < 16; i++) {
            int kk = 4 * i + tc;
            float v = xcol[(size_t)(k0 + kk) * HW];
            unsigned short h = bf16rne(v);
            float hf = __uint_as_float((unsigned)h << 16);
            xs[0][tl][kk] = h;
            xs[1][tl][kk] = bf16rne(v - hf);
        }
        #pragma unroll
        for (int i = 0; i < 12; i++) {
            int idx = tid + i * 256;          // 0..3071 (2 planes * 96 o * 16 ushort4)
            int plane = idx / 1536;
            int rem   = idx - plane * 1536;
            int o     = rem >> 4;
            int j     = rem & 15;
            const unsigned short* src = (plane ? wLo : wHi) + o * 256 + k0 + 4 * j;
            *(uint2*)&wsb[plane][o][4 * j] = *(const uint2*)src;
        }
        __syncthreads();
        #pragma unroll
        for (int ks = 0; ks < 64; ks += 32) {
            bf16x8 ah = *(const bf16x8*)&xs[0][16 * wv + n16][q * 8 + ks];
            bf16x8 al = *(const bf16x8*)&xs[1][16 * wv + n16][q * 8 + ks];
            #pragma unroll
            for (int t = 0; t < 6; t++) {
                bf16x8 bh = *(const bf16x8*)&wsb[0][16 * t + n16][q * 8 + ks];
                bf16x8 bl = *(const bf16x8*)&wsb[1][16 * t + n16][q * 8 + ks];
                acc[t] = __builtin_amdgcn_mfma_f32_16x16x32_bf16(ah, bh, acc[t], 0, 0, 0);
                acc[t] = __builtin_amdgcn_mfma_f32_16x16x32_bf16(ah, bl, acc[t], 0, 0, 0);
                acc[t] = __builtin_amdgcn_mfma_f32_16x16x32_bf16(al, bh, acc[t], 0, 0, 0);
            }
        }
    }

    float bias[6];
    #pragma unroll
    for (int t = 0; t < 6; t++) bias[t] = b_dep[16 * t + n16];
    #pragma unroll
    for (int r = 0; r < 4; r++) {
        int pxg = pxg0 + 16 * wv + 4 * q + r;
        float* yp = yT + (size_t)pxg * NOUT;
        float v0 = acc[0][r] + bias[0];
        float mx = v0;
        #pragma unroll
        for (int m = 1; m < 16; m <<= 1) mx = fmaxf(mx, __shfl_xor(mx, m));
        float e = expf(v0 - mx);
        float s = e;
        #pragma unroll
        for (int m = 1; m < 16; m <<= 1) s += __shfl_xor(s, m);
        yp[n16] = e / s;
        #pragma unroll
        for (int t = 1; t < 6; t++) yp[16 * t + n16] = acc[t][r] + bias[t];
    }
}

// ---------------- 7. chunked segmented gather, 4-deep software pipeline -----------
// Wave = 64 CSR positions. plist/pcell register-cached (one coalesced load each),
// broadcast via shfl. Points processed in groups of 4: all 12 loads issued before
// the flush/accumulate sequence -> MLP 12 (was 1: flush branch serialized loads).
// Accumulation order over j unchanged -> bitwise-identical bev.
__global__ __launch_bounds__(256) void lss_gather_kernel(const float* __restrict__ yT,
                                                         const int* __restrict__ plist,
                                                         const int* __restrict__ pcell,
                                                         const int* __restrict__ nvptr,
                                                         float* __restrict__ bevHWC) {
    int wv   = threadIdx.x >> 6;
    int lane = threadIdx.x & 63;
    int pos0 = (blockIdx.x * 4 + wv) * 64;
    int nv = *nvptr;
    if (pos0 >= nv) return;
    int n = min(64, nv - pos0);
    int gp = pos0 + lane;
    int myp = (gp < nv) ? plist[gp] : 0;
    int myc = (gp < nv) ? pcell[gp] : -1;
    int l16 = lane & 15;

    float a0 = 0.f, a1 = 0.f;
    int cur = __shfl(myc, 0);
    int j = 0;
    for (; j + 4 <= n; j += 4) {
        int   pf[4], cc[4];
        float av[4], bv[4], dv[4];
        #pragma unroll
        for (int u = 0; u < 4; u++) {
            pf[u] = __shfl(myp, j + u);
            cc[u] = __shfl(myc, j + u);
        }
        #pragma unroll
        for (int u = 0; u < 4; u++) {
            const float* rp = yT + (size_t)(pf[u] >> 4) * NOUT;
            av[u] = rp[16 + lane];
            bv[u] = rp[80 + l16];          // lanes>=16 compute unused values
            dv[u] = rp[pf[u] & 15];        // wave-uniform broadcast
        }
        #pragma unroll
        for (int u = 0; u < 4; u++) {
            if (cc[u] != cur) {
                atomicAdd(&bevHWC[(size_t)cur * COUT + lane], a0);
                if (lane < 16) atomicAdd(&bevHWC[(size_t)cur * COUT + 64 + lane], a1);
                a0 = a1 = 0.f;
                cur = cc[u];
            }
            a0 = fmaf(dv[u], av[u], a0);
            a1 = fmaf(dv[u], bv[u], a1);
        }
    }
    for (; j < n; j++) {
        int pf = __shfl(myp, j);
        int c  = __shfl(myc, j);
        const float* rp = yT + (size_t)(pf >> 4) * NOUT;
        float aval = rp[16 + lane];
        float bval = rp[80 + l16];
        float dep  = rp[pf & 15];
        if (c != cur) {
            atomicAdd(&bevHWC[(size_t)cur * COUT + lane], a0);
            if (lane < 16) atomicAdd(&bevHWC[(size_t)cur * COUT + 64 + lane], a1);
            a0 = a1 = 0.f;
            cur = c;
        }
        a0 = fmaf(dep, aval, a0);
        a1 = fmaf(dep, bval, a1);
    }
    atomicAdd(&bevHWC[(size_t)cur * COUT + lane], a0);
    if (lane < 16) atomicAdd(&bevHWC[(size_t)cur * COUT + 64 + lane], a1);
}

// ---------------- 8. transpose HWC->CHW + normalize by count ----------------------
__global__ __launch_bounds__(256) void lss_tr_kernel(const float* __restrict__ bevHWC,
                                                     const int* __restrict__ counts,
                                                     float* __restrict__ bevCHW) {
    __shared__ float t[COUT][65];
    __shared__ float ic[64];
    int tid = threadIdx.x;
    int cellbase = blockIdx.x * 64;
    if (tid < 64) {
        int cnt = counts[cellbase + tid];
        ic[tid] = 1.f / fmaxf((float)cnt, 1.f);
    }
    const float* src = bevHWC + (size_t)cellbase * COUT;
    #pragma unroll
    for (int k = 0; k < 20; k++) {
        int idx = tid + k * 256;           // 5120 = 20*256
        int yx = idx / COUT, ch = idx % COUT;
        t[ch][yx] = src[idx];
    }
    __syncthreads();
    int b  = cellbase >> 14;
    int yx0 = cellbase & 16383;
    #pragma unroll
    for (int k = 0; k < 20; k++) {
        int idx = tid + k * 256;
        int ch = idx / 64, yxl = idx % 64;
        bevCHW[((size_t)(b * COUT + ch)) * (BEVH * BEVW) + yx0 + yxl] = t[ch][yxl] * ic[yxl];
    }
}

// ---------------- 9. 3x3 conv via split-bf16 MFMA implicit GEMM -------------------
__global__ __launch_bounds__(256) void lss_conv_kernel(const float* __restrict__ bev,
                                                       const unsigned short* __restrict__ wrh,
                                                       const unsigned short* __restrict__ wrl,
                                                       const float* __restrict__ bias,
                                                       float* __restrict__ out) {
    __shared__ unsigned short inT[2][10][10][104];
    int tid = threadIdx.x;
    int blk = blockIdx.x;                  // 512
    int b   = blk >> 8;
    int y0  = ((blk >> 4) & 15) * 8;
    int x0  = (blk & 15) * 8;
    int lane = tid & 63, w = tid >> 6;
    int q = lane >> 4, n16 = lane & 15;
    int ow = w >> 1;                        // 0: o 0..47 (3 tiles), 1: o 48..79 (2)
    int pj = (w & 1) * 2;                   // px-tile pair base (each tile = 2 rows x 8)
    int pr = n16 >> 3, pc = n16 & 7;
    int NO = ow ? 2 : 3;
    int obase = ow * 48;
    int kq = 8 * q;
    int rowb0 = 2 * pj + pr;

    int woff[3];
    #pragma unroll
    for (int i = 0; i < 3; i++) woff[i] = (obase + 16 * i + n16) * 864 + kq;

    f32x4 acc[3][2];
    #pragma unroll
    for (int i = 0; i < 3; i++)
        #pragma unroll
        for (int j = 0; j < 2; j++) acc[i][j] = (f32x4){0.f, 0.f, 0.f, 0.f};

    const float* pb = bev + (size_t)b * COUT * (BEVH * BEVW);

    for (int cc = 0; cc < 3; cc++) {
        int ci0 = cc * 32;
        if (cc) __syncthreads();
        #pragma unroll
        for (int t = 0; t < 13; t++) {
            int idx = tid + t * 256;       // 3200 = 32 ci x 10 x 10
            if (idx < 3200) {
                int ci  = idx / 100;
                int rem = idx - ci * 100;
                int r   = rem / 10;
                int c   = rem - r * 10;
                int gy = y0 + r - 1, gx = x0 + c - 1;
                int gci = ci0 + ci;
                float v = 0.f;
                if (gy >= 0 && gy < BEVH && gx >= 0 && gx < BEVW && gci < COUT)
                    v = pb[((size_t)gci * BEVH + gy) * BEVW + gx];
                unsigned short h = bf16rne(v);
                float hf = __uint_as_float((unsigned)h << 16);
                inT[0][r][c][ci] = h;
                inT[1][r][c][ci] = bf16rne(v - hf);
            }
        }
        __syncthreads();
        #pragma unroll
        for (int s = 0; s < 9; s++) {
            int dy = s / 3, dx = s - dy * 3;
            int kb = s * 96 + ci0;
            bf16x8 bh[2], bl[2];
            #pragma unroll
            for (int j = 0; j < 2; j++) {
                int rr = rowb0 + 2 * j + dy;
                int ccol = pc + dx;
                bh[j] = *(const bf16x8*)&inT[0][rr][ccol][kq];
                bl[j] = *(const bf16x8*)&inT[1][rr][ccol][kq];
            }
            #pragma unroll
            for (int i = 0; i < 3; i++) {
                if (i < NO) {
                    bf16x8 ah = *(const bf16x8*)&wrh[woff[i] + kb];
                    bf16x8 al = *(const bf16x8*)&wrl[woff[i] + kb];
                    #pragma unroll
                    for (int j = 0; j < 2; j++) {
                        acc[i][j] = __builtin_amdgcn_mfma_f32_16x16x32_bf16(ah, bh[j], acc[i][j], 0, 0, 0);
                        acc[i][j] = __builtin_amdgcn_mfma_f32_16x16x32_bf16(ah, bl[j], acc[i][j], 0, 0, 0);
                        acc[i][j] = __builtin_amdgcn_mfma_f32_16x16x32_bf16(al, bh[j], acc[i][j], 0, 0, 0);
                    }
                }
            }
        }
    }
    #pragma unroll
    for (int i = 0; i < 3; i++) {
        if (i < NO) {
            #pragma unroll
            for (int j = 0; j < 2; j++) {
                int gy = y0 + 2 * (pj + j) + pr;
                int gx = x0 + pc;
                #pragma unroll
                for (int r = 0; r < 4; r++) {
                    int o = obase + 16 * i + 4 * q + r;
                    out[((size_t)(b * COUT + o) * BEVH + gy) * BEVW + gx] = acc[i][j][r] + bias[o];
                }
            }
        }
    }
}

// ---------------- launch ----------------
extern "C" void kernel_launch(void* const* d_in, const int* in_sizes, int n_in,
                              void* d_out, int out_size, void* d_ws, size_t ws_size,
                              hipStream_t stream) {
    (void)in_sizes; (void)n_in; (void)out_size; (void)ws_size;
    const float* x     = (const float*)d_in[0];
    const float* l2i   = (const float*)d_in[1];
    const float* aug   = (const float*)d_in[2];
    const float* w_dep = (const float*)d_in[3];
    const float* b_dep = (const float*)d_in[4];
    const float* w_ref = (const float*)d_in[5];
    const float* b_ref = (const float*)d_in[6];
    float* out = (float*)d_out;

    char* ws = (char*)d_ws;
    float* mats    = (float*)(ws + MATS_OFF);
    unsigned short* wHi = (unsigned short*)(ws + WHI_OFF);
    unsigned short* wLo = (unsigned short*)(ws + WLO_OFF);
    unsigned short* wrh = (unsigned short*)(ws + WRH_OFF);
    unsigned short* wrl = (unsigned short*)(ws + WRL_OFF);
    float* yT      = (float*)(ws + YT_OFF);     // reused as bevCHW after gather
    float* bevCHW  = (float*)(ws + YT_OFF);
    int*   cellid  = (int*)(ws + CELL_OFF);
    int*   counts  = (int*)(ws + COUNTS_OFF);
    int*   starts  = (int*)(ws + STARTS_OFF);
    int*   cursors = (int*)(ws + CURS_OFF);
    int*   plist   = (int*)(ws + PLIST_OFF);
    int*   pcell   = (int*)(ws + PCELL_OFF);
    float* bevHWC  = (float*)(ws + BEVHWC_OFF);

    hipMemsetAsync(counts, 0, NUMC * sizeof(int), stream);
    hipMemsetAsync(bevHWC, 0, (size_t)NUMC * COUT * sizeof(float), stream);
    lss_prep_kernel<<<1, 64, 0, stream>>>(l2i, aug, mats);
    lss_wt_kernel<<<96, 256, 0, stream>>>(w_dep, wHi, wLo);
    lss_wref_kernel<<<270, 256, 0, stream>>>(w_ref, wrh, wrl);
    lss_geom_kernel<<<BN * HW / 256, 256, 0, stream>>>(mats, cellid, counts);
    lss_scan_kernel<<<1, 1024, 0, stream>>>(counts, starts, cursors);
    lss_fill_kernel<<<NPTS / 256, 256, 0, stream>>>(cellid, cursors, plist, pcell);
    lss_gemm_kernel<<<528, 256, 0, stream>>>(x, wHi, wLo, b_dep, yT);
    lss_gather_kernel<<<NPTS / 256, 256, 0, stream>>>(yT, plist, pcell, starts + NUMC, bevHWC);
    lss_tr_kernel<<<NUMC / 64, 256, 0, stream>>>(bevHWC, counts, bevCHW);
    lss_conv_kernel<<<512, 256, 0, stream>>>(bevCHW, wrh, wrl, b_ref, out);
}